// Round 6
// baseline (1052.409 us; speedup 1.0000x reference)
//
#include <hip/hip_runtime.h>
#include <hip/hip_bf16.h>

namespace {

constexpr int B   = 1024;
constexpr int PEP = 15;
constexpr int MHCN = 44;
constexpr int S   = 59;    // sequence
constexpr int V   = 21;    // vocab / model dim
constexpr int C   = 3200;  // conv channels
constexpr int KW  = 9;     // depthwise kernel
constexpr int H   = 9;     // heads
constexpr int NH  = 800;
constexpr int SV  = S * V;   // 1239
constexpr int HD  = H * V;   // 189
constexpr float EPSF = 1e-5f;

__device__ __forceinline__ float sigm(float x) {
  // v_rcp_f32 instead of IEEE divide expansion (~1ulp, fine for sigmoid)
  return __builtin_amdgcn_rcpf(1.f + __expf(-x));
}

// ---------------- K0: pack per-channel conv-module params ----------------
// Per-channel record (stride 88 floats = 352B, 16B aligned):
//   [0..20]  wa = W1[c]          [24..44] wg = W1[c+C]
//   [48..56] wd[9]   [57] ba  [58] bg  [59] sc2  [60] sh2
//   [64..84] w2t = W2[:, c]
constexpr int PKS = 88;
__global__ void k_pack(const float* __restrict__ W1, const float* __restrict__ b1,
                       const float* __restrict__ Wd, const float* __restrict__ bd,
                       const float* __restrict__ g, const float* __restrict__ bb,
                       const float* __restrict__ m, const float* __restrict__ vv,
                       const float* __restrict__ W2, float* __restrict__ pk) {
  int c = blockIdx.x * 64 + threadIdx.x;
  if (c >= C) return;
  float* p = pk + (size_t)c * PKS;
  for (int i = 0; i < V; ++i) p[i] = W1[c * V + i];
  for (int i = 0; i < V; ++i) p[24 + i] = W1[(c + C) * V + i];
  for (int k = 0; k < KW; ++k) p[48 + k] = Wd[c * KW + k];
  float sc = g[c] * rsqrtf(vv[c] + EPSF);
  p[57] = b1[c];
  p[58] = b1[c + C];
  p[59] = sc;
  p[60] = (bd[c] - m[c]) * sc + bb[c];
  for (int i = 0; i < V; ++i) p[64 + i] = W2[(size_t)i * C + c];
}

// ---------------- K2: fused concat + conv module + residual + LN -> X1 ----------------
// One block per batch element, 8 waves. lane = sequence position, wave-uniform
// channel; weights arrive as scalar loads.
// R5 lesson: VGPR_Count=28 -> x[21] was NOT register-resident (remat reload /
// AGPR round-trip each channel => ~223 VALU insts/chan vs ~85 useful).
// Fix: (a) amdgpu_waves_per_eu(2,4) caps allocator's occupancy target so the
// VGPR budget is ~512, (b) opaque asm pins make x/yac non-rematerializable.
// NO unroll pragma on the channel loop (cross-lane LDS RAW hazard - R3 failure).
__global__ __launch_bounds__(512) __attribute__((amdgpu_waves_per_eu(2, 4)))
void k_conv(
    const float* __restrict__ pep, const float* __restrict__ mhc,
    const float* __restrict__ pack,
    const float* __restrict__ b2, const float* __restrict__ lng,
    const float* __restrict__ lnb, float* __restrict__ X1) {
  __shared__ float grow[8][72];      // per-wave depthwise exchange row (4-zero halo each side)
  __shared__ float part[4][64 * V];  // paired-wave down-proj partials
  __shared__ float yfull[SV];        // reduced down-proj output
  const int t = threadIdx.x;
  const int b = blockIdx.x;
  const int lane = t & 63;
  const int w = __builtin_amdgcn_readfirstlane(t >> 6);

  for (int i = t; i < 8 * 72; i += 512) (&grow[0][0])[i] = 0.f;

  // persistent registers: input row (concat of pep/mhc) + down-proj accumulator
  const int row = lane < S ? lane : S - 1;
  const float* xr = (row < PEP) ? pep + ((size_t)b * PEP + row) * V
                                : mhc + ((size_t)b * MHCN + (row - PEP)) * V;
  float x[V];
#pragma unroll
  for (int v = 0; v < V; ++v) x[v] = xr[v];
#pragma unroll
  for (int v = 0; v < V; ++v) asm volatile("" : "+v"(x[v]));  // pin: no remat
  float yac[V];
#pragma unroll
  for (int v = 0; v < V; ++v) yac[v] = 0.f;
#pragma unroll
  for (int v = 0; v < V; ++v) asm volatile("" : "+v"(yac[v]));  // pin
  __syncthreads();

  const bool wr = lane < S;
  for (int i = 0; i < C / 8; ++i) {
    const int c = 8 * i + w;  // wave-uniform channel
    const float* p = pack + (size_t)c * PKS;
    // ---- GLU ----
    float a = p[57], g = p[58];
#pragma unroll
    for (int v = 0; v < V; ++v) a = fmaf(x[v], p[v], a);
#pragma unroll
    for (int v = 0; v < V; ++v) g = fmaf(x[v], p[24 + v], g);
    const float gl = a * sigm(g);
    if (wr) grow[w][4 + lane] = gl;  // wave-synchronous: same wave consumes below
    // ---- depthwise conv + BN + SiLU ----
    float acc = 0.f;
#pragma unroll
    for (int k = 0; k < KW; ++k) acc = fmaf(grow[w][lane + k], p[48 + k], acc);
    acc = fmaf(acc, p[59], p[60]);
    const float sbv = acc * sigm(acc);
    // ---- down-projection accumulate (registers) ----
#pragma unroll
    for (int v = 0; v < V; ++v) yac[v] = fmaf(sbv, p[64 + v], yac[v]);
  }

  // deterministic two-stage cross-wave reduction
  if (w >= 4) {
#pragma unroll
    for (int v = 0; v < V; ++v) part[w - 4][lane * V + v] = yac[v];
  }
  __syncthreads();
  if (w < 4) {
#pragma unroll
    for (int v = 0; v < V; ++v) part[w][lane * V + v] += yac[v];
  }
  __syncthreads();
  for (int e = t; e < SV; e += 512)
    yfull[e] = (part[0][e] + part[1][e]) + (part[2][e] + part[3][e]);
  __syncthreads();

  // residual + b2 + LayerNorm over V (x[] regs still hold the residual row)
  if (t < S) {
    float z[V];
    float mn = 0.f;
#pragma unroll
    for (int v = 0; v < V; ++v) {
      z[v] = x[v] + yfull[t * V + v] + b2[v];
      mn += z[v];
    }
    mn *= (1.f / V);
    float var = 0.f;
#pragma unroll
    for (int v = 0; v < V; ++v) {
      float d = z[v] - mn;
      var = fmaf(d, d, var);
    }
    const float inv = rsqrtf(var * (1.f / V) + EPSF);
#pragma unroll
    for (int v = 0; v < V; ++v)
      X1[(size_t)b * SV + t * V + v] = (z[v] - mn) * inv * lng[v] + lnb[v];
  }
}

// ---------------- K3: per-(b,h) attention -> O [B,59,189] ----------------
// lane = row. x row + q row in registers; QKV weights read as wave-uniform
// s_loads straight from global (never staged); only k/v rows + score rows in
// LDS. Lanes 59..63 duplicate row 58 (identical values -> benign LDS dup write).
__global__ __launch_bounds__(64) __attribute__((amdgpu_waves_per_eu(1, 8)))
void k_attn(
    const float* __restrict__ X1, const float* __restrict__ Wq, const float* __restrict__ Wk,
    const float* __restrict__ Wv, float* __restrict__ O) {
  __shared__ float ks[SV], vs[SV];
  __shared__ float ss[S * 61];  // score rows, odd stride
  const int lane = threadIdx.x;
  const int bh = blockIdx.x;
  const int b = bh / H;
  const int h = bh - b * H;
  const int row = lane < S ? lane : S - 1;

  float x[V];
  {
    const float* xr = X1 + (size_t)b * SV + row * V;
#pragma unroll
    for (int u = 0; u < V; ++u) x[u] = xr[u];
#pragma unroll
    for (int u = 0; u < V; ++u) asm volatile("" : "+v"(x[u]));  // pin: no remat
  }
  const float* wqh = Wq + h * V;
  const float* wkh = Wk + h * V;
  const float* wvh = Wv + h * V;
  float q[V];
  for (int d = 0; d < V; ++d) {
    float qa = 0.f, ka = 0.f, va = 0.f;
#pragma unroll
    for (int u = 0; u < V; ++u) {
      const float xv = x[u];
      qa = fmaf(xv, wqh[u * HD + d], qa);  // weight addr wave-uniform -> s_load
      ka = fmaf(xv, wkh[u * HD + d], ka);
      va = fmaf(xv, wvh[u * HD + d], va);
    }
    q[d] = qa;
    ks[row * V + d] = ka;   // lanes 59-63 rewrite row 58 with identical values
    vs[row * V + d] = va;
  }
  __syncthreads();

  if (lane < S) {
    const float rs = 0.21821789023599236f;  // 1/sqrt(21)
    float mx = -1e30f;
    for (int j = 0; j < S; ++j) {
      float acc = 0.f;
#pragma unroll
      for (int d = 0; d < V; ++d) acc = fmaf(q[d], ks[j * V + d], acc);
      acc *= rs;
      ss[lane * 61 + j] = acc;
      mx = fmaxf(mx, acc);
    }
    float sum = 0.f;
    for (int j = 0; j < S; ++j) {
      float e = __expf(ss[lane * 61 + j] - mx);
      ss[lane * 61 + j] = e;
      sum += e;
    }
    const float inv = __builtin_amdgcn_rcpf(sum);
    float o[V];
#pragma unroll
    for (int d = 0; d < V; ++d) o[d] = 0.f;
    for (int j = 0; j < S; ++j) {
      const float p = ss[lane * 61 + j];
#pragma unroll
      for (int d = 0; d < V; ++d) o[d] = fmaf(p, vs[j * V + d], o[d]);
    }
    float* op = O + (size_t)(b * S + lane) * HD + h * V;
#pragma unroll
    for (int d = 0; d < V; ++d) op[d] = o[d] * inv;
  }
}

// ---------------- K4: O @ Wo + residual + LN -> X2 ----------------
__global__ __launch_bounds__(128) void k_wo(
    const float* __restrict__ O, const float* __restrict__ Wo, const float* __restrict__ X1,
    const float* __restrict__ lng, const float* __restrict__ lnb, float* __restrict__ X2) {
  __shared__ float Ws[HD * V];
  __shared__ float yo[SV];
  const int t = threadIdx.x;
  const int b = blockIdx.x;
  for (int i = t; i < HD * V; i += 128) Ws[i] = Wo[i];
  __syncthreads();
  for (int i = t; i < SV; i += 128) {
    int l = i / V, v = i - l * V;
    const float* orow = O + (size_t)(b * S + l) * HD;
    float acc = 0;
#pragma unroll 9
    for (int m = 0; m < HD; ++m) acc = fmaf(orow[m], Ws[m * V + v], acc);
    yo[i] = acc;
  }
  __syncthreads();
  if (t < S) {
    float z[V];
    float m = 0;
#pragma unroll
    for (int v = 0; v < V; ++v) {
      z[v] = X1[b * SV + t * V + v] + yo[t * V + v];
      m += z[v];
    }
    m *= (1.f / V);
    float var = 0;
#pragma unroll
    for (int v = 0; v < V; ++v) {
      float d = z[v] - m;
      var = fmaf(d, d, var);
    }
    const float inv = rsqrtf(var * (1.f / V) + EPSF);
#pragma unroll
    for (int v = 0; v < V; ++v)
      X2[b * SV + t * V + v] = (z[v] - m) * inv * lng[v] + lnb[v];
  }
}

// ---------------- K5: head GEMM [B,1239]@[1239,800] + bias + silu + BN -> Hb ----------------
constexpr int BT = 8;    // batch rows per block
constexpr int NT = 200;  // output cols per block
__global__ __launch_bounds__(256) void k_f1(
    const float* __restrict__ X2, const float* __restrict__ Wf1, const float* __restrict__ bf1,
    const float* __restrict__ g2, const float* __restrict__ bb2, const float* __restrict__ m2,
    const float* __restrict__ v2, float* __restrict__ Hb) {
  __shared__ __align__(16) float Xs[BT * 1240];
  const int t = threadIdx.x;
  const int bbase = blockIdx.x * BT;
  const int nbase = blockIdx.y * NT;
  for (int i = t; i < BT * SV; i += 256) {
    int r = i / SV, f = i - r * SV;
    Xs[r * 1240 + f] = X2[(size_t)(bbase + r) * SV + f];
  }
  __syncthreads();
  if (t < NT) {
    const int n = nbase + t;
    float acc[BT];
#pragma unroll
    for (int r = 0; r < BT; ++r) acc[r] = 0.f;
    int f = 0;
    for (; f + 3 < SV; f += 4) {
      const float w0 = Wf1[(size_t)f * NH + n];
      const float w1 = Wf1[(size_t)(f + 1) * NH + n];
      const float w2 = Wf1[(size_t)(f + 2) * NH + n];
      const float w3 = Wf1[(size_t)(f + 3) * NH + n];
#pragma unroll
      for (int r = 0; r < BT; ++r) {
        const float4 x = *reinterpret_cast<const float4*>(&Xs[r * 1240 + f]);
        acc[r] = fmaf(x.x, w0, acc[r]);
        acc[r] = fmaf(x.y, w1, acc[r]);
        acc[r] = fmaf(x.z, w2, acc[r]);
        acc[r] = fmaf(x.w, w3, acc[r]);
      }
    }
    for (; f < SV; ++f) {
      const float w0 = Wf1[(size_t)f * NH + n];
#pragma unroll
      for (int r = 0; r < BT; ++r) acc[r] = fmaf(Xs[r * 1240 + f], w0, acc[r]);
    }
    const float sc = g2[n] * rsqrtf(v2[n] + EPSF);
    const float sh = bb2[n] - m2[n] * sc;
    const float bias = bf1[n];
#pragma unroll
    for (int r = 0; r < BT; ++r) {
      float hh = acc[r] + bias;
      hh = hh * sigm(hh);            // silu
      hh = fmaf(hh, sc, sh);         // BN2 (inference)
      Hb[(size_t)(bbase + r) * NH + n] = hh;
    }
  }
}

// ---------------- K6: relu(Hb@Wf2+bf2) @ Wf3 + bf3 -> out [B,2] ----------------
__global__ __launch_bounds__(64) void k_f23(
    const float* __restrict__ Hb, const float* __restrict__ Wf2, const float* __restrict__ bf2,
    const float* __restrict__ Wf3, const float* __restrict__ bf3, float* __restrict__ out) {
  __shared__ __align__(16) float hs[NH];
  const int t = threadIdx.x;
  const int b = blockIdx.x;
  for (int i = t; i < NH; i += 64) hs[i] = Hb[(size_t)b * NH + i];
  __syncthreads();
  float acc = bf2[t];
  for (int n = 0; n < NH; n += 4) {
    const float4 hv = *reinterpret_cast<const float4*>(&hs[n]);
    acc = fmaf(hv.x, Wf2[n * 64 + t], acc);
    acc = fmaf(hv.y, Wf2[(n + 1) * 64 + t], acc);
    acc = fmaf(hv.z, Wf2[(n + 2) * 64 + t], acc);
    acc = fmaf(hv.w, Wf2[(n + 3) * 64 + t], acc);
  }
  const float mid = fmaxf(acc, 0.f);
  float p0 = mid * Wf3[t * 2 + 0];
  float p1 = mid * Wf3[t * 2 + 1];
#pragma unroll
  for (int off = 32; off > 0; off >>= 1) {
    p0 += __shfl_down(p0, off);
    p1 += __shfl_down(p1, off);
  }
  if (t == 0) {
    out[b * 2 + 0] = p0 + bf3[0];
    out[b * 2 + 1] = p1 + bf3[1];
  }
}

}  // namespace

extern "C" void kernel_launch(void* const* d_in, const int* in_sizes, int n_in,
                              void* d_out, int out_size, void* d_ws, size_t ws_size,
                              hipStream_t stream) {
  const float* pep   = (const float*)d_in[0];
  const float* mhc   = (const float*)d_in[1];
  const float* W1    = (const float*)d_in[2];
  const float* b1    = (const float*)d_in[3];
  const float* Wd    = (const float*)d_in[4];
  const float* bd    = (const float*)d_in[5];
  const float* bn1_g = (const float*)d_in[6];
  const float* bn1_b = (const float*)d_in[7];
  const float* bn1_m = (const float*)d_in[8];
  const float* bn1_v = (const float*)d_in[9];
  const float* W2    = (const float*)d_in[10];
  const float* b2    = (const float*)d_in[11];
  const float* ln_g  = (const float*)d_in[12];
  const float* ln_b  = (const float*)d_in[13];
  const float* Wq    = (const float*)d_in[14];
  const float* Wk    = (const float*)d_in[15];
  const float* Wv    = (const float*)d_in[16];
  const float* Wo    = (const float*)d_in[17];
  const float* Wf1   = (const float*)d_in[18];
  const float* bf1   = (const float*)d_in[19];
  const float* bn2_g = (const float*)d_in[20];
  const float* bn2_b = (const float*)d_in[21];
  const float* bn2_m = (const float*)d_in[22];
  const float* bn2_v = (const float*)d_in[23];
  const float* Wf2   = (const float*)d_in[24];
  const float* bf2   = (const float*)d_in[25];
  const float* Wf3   = (const float*)d_in[26];
  const float* bf3   = (const float*)d_in[27];
  float* out = (float*)d_out;

  float* ws = (float*)d_ws;
  float* X1 = ws;                          // [B,59,21]
  float* X2 = X1 + (size_t)B * SV;         // [B,59,21]
  float* O  = X2 + (size_t)B * SV;         // [B,59,189]
  float* Hb = O + (size_t)B * S * HD;      // [B,800]
  float* Pk = Hb + (size_t)B * NH;         // [C,88] packed conv params

  k_pack<<<(C + 63) / 64, 64, 0, stream>>>(W1, b1, Wd, bd, bn1_g, bn1_b, bn1_m, bn1_v, W2, Pk);
  k_conv<<<B, 512, 0, stream>>>(pep, mhc, Pk, b2, ln_g, ln_b, X1);
  k_attn<<<B * H, 64, 0, stream>>>(X1, Wq, Wk, Wv, O);
  k_wo<<<B, 128, 0, stream>>>(O, Wo, X1, ln_g, ln_b, X2);
  dim3 g5(B / BT, NH / NT);
  k_f1<<<g5, 256, 0, stream>>>(X2, Wf1, bf1, bn2_g, bn2_b, bn2_m, bn2_v, Hb);
  k_f23<<<B, 64, 0, stream>>>(Hb, Wf2, bf2, Wf3, bf3, out);
}

// Round 7
// 918.167 us; speedup vs baseline: 1.1462x; 1.1462x over previous
//
#include <hip/hip_runtime.h>
#include <hip/hip_bf16.h>

namespace {

constexpr int B   = 1024;
constexpr int PEP = 15;
constexpr int MHCN = 44;
constexpr int S   = 59;    // sequence
constexpr int V   = 21;    // vocab / model dim
constexpr int C   = 3200;  // conv channels
constexpr int KW  = 9;     // depthwise kernel
constexpr int H   = 9;     // heads
constexpr int NH  = 800;
constexpr int SV  = S * V;   // 1239
constexpr int HD  = H * V;   // 189
constexpr float EPSF = 1e-5f;

__device__ __forceinline__ float sigm(float x) {
  // v_rcp_f32 instead of IEEE divide expansion (~1ulp, fine for sigmoid)
  return __builtin_amdgcn_rcpf(1.f + __expf(-x));
}

// ---------------- K0: pack per-channel conv-module params ----------------
// Per-channel record (stride 88 floats = 352B, 16B aligned):
//   [0..20]  wa = W1[c]          [24..44] wg = W1[c+C]
//   [48..56] wd[9]*bnscale   [57] ba  [58] bg  [59] (unused)  [60] sh2
//   [64..84] w2t = W2[:, c]
constexpr int PKS = 88;
__global__ void k_pack(const float* __restrict__ W1, const float* __restrict__ b1,
                       const float* __restrict__ Wd, const float* __restrict__ bd,
                       const float* __restrict__ g, const float* __restrict__ bb,
                       const float* __restrict__ m, const float* __restrict__ vv,
                       const float* __restrict__ W2, float* __restrict__ pk) {
  int c = blockIdx.x * 64 + threadIdx.x;
  if (c >= C) return;
  float* p = pk + (size_t)c * PKS;
  float sc = g[c] * rsqrtf(vv[c] + EPSF);
  for (int i = 0; i < V; ++i) p[i] = W1[c * V + i];
  for (int i = 0; i < V; ++i) p[24 + i] = W1[(c + C) * V + i];
  for (int k = 0; k < KW; ++k) p[48 + k] = Wd[c * KW + k] * sc;  // BN scale folded into taps
  p[57] = b1[c];
  p[58] = b1[c + C];
  p[59] = sc;
  p[60] = (bd[c] - m[c]) * sc + bb[c];
  for (int i = 0; i < V; ++i) p[64 + i] = W2[(size_t)i * C + c];
}

// ---------------- K2: fused concat + conv module + residual + LN -> X1 ----------------
// One block per batch element, 8 waves. lane = sequence position, wave-uniform
// channel; weights arrive as scalar loads.
// R4 lesson: bare launch_bounds(512) -> VGPR_Count=28, x[21]/yac[21] NOT
// resident (remat/AGPR round trip, ~448cy/chan vs ~188 ideal).
// R6 lesson: asm pins force residency (VGPR 52) but waves_per_eu(2,4)'s max=4
// capped occupancy at 36% -> latency-bound, net regression.
// R7: pins WITHOUT the occupancy cap.
// NO unroll pragma on the channel loop (cross-lane LDS RAW hazard - R3 failure).
__global__ __launch_bounds__(512)
void k_conv(
    const float* __restrict__ pep, const float* __restrict__ mhc,
    const float* __restrict__ pack,
    const float* __restrict__ b2, const float* __restrict__ lng,
    const float* __restrict__ lnb, float* __restrict__ X1) {
  __shared__ float grow[8][72];      // per-wave depthwise exchange row (4-zero halo each side)
  __shared__ float part[4][64 * V];  // paired-wave down-proj partials
  __shared__ float yfull[SV];        // reduced down-proj output
  const int t = threadIdx.x;
  const int b = blockIdx.x;
  const int lane = t & 63;
  const int w = __builtin_amdgcn_readfirstlane(t >> 6);

  for (int i = t; i < 8 * 72; i += 512) (&grow[0][0])[i] = 0.f;

  // persistent registers: input row (concat of pep/mhc) + down-proj accumulator
  const int row = lane < S ? lane : S - 1;
  const float* xr = (row < PEP) ? pep + ((size_t)b * PEP + row) * V
                                : mhc + ((size_t)b * MHCN + (row - PEP)) * V;
  float x[V];
#pragma unroll
  for (int v = 0; v < V; ++v) x[v] = xr[v];
#pragma unroll
  for (int v = 0; v < V; ++v) asm volatile("" : "+v"(x[v]));  // pin: no remat
  float yac[V];
#pragma unroll
  for (int v = 0; v < V; ++v) yac[v] = 0.f;
#pragma unroll
  for (int v = 0; v < V; ++v) asm volatile("" : "+v"(yac[v]));  // pin
  __syncthreads();

  const bool wr = lane < S;
  for (int i = 0; i < C / 8; ++i) {
    const int c = 8 * i + w;  // wave-uniform channel
    const float* p = pack + (size_t)c * PKS;
    // ---- GLU ----
    float a = p[57], g = p[58];
#pragma unroll
    for (int v = 0; v < V; ++v) a = fmaf(x[v], p[v], a);
#pragma unroll
    for (int v = 0; v < V; ++v) g = fmaf(x[v], p[24 + v], g);
    const float gl = a * sigm(g);
    if (wr) grow[w][4 + lane] = gl;  // wave-synchronous: same wave consumes below
    // ---- depthwise conv (BN scale pre-folded into taps) + shift + SiLU ----
    float acc = p[60];
#pragma unroll
    for (int k = 0; k < KW; ++k) acc = fmaf(grow[w][lane + k], p[48 + k], acc);
    const float sbv = acc * sigm(acc);
    // ---- down-projection accumulate (registers) ----
#pragma unroll
    for (int v = 0; v < V; ++v) yac[v] = fmaf(sbv, p[64 + v], yac[v]);
  }

  // deterministic two-stage cross-wave reduction
  if (w >= 4) {
#pragma unroll
    for (int v = 0; v < V; ++v) part[w - 4][lane * V + v] = yac[v];
  }
  __syncthreads();
  if (w < 4) {
#pragma unroll
    for (int v = 0; v < V; ++v) part[w][lane * V + v] += yac[v];
  }
  __syncthreads();
  for (int e = t; e < SV; e += 512)
    yfull[e] = (part[0][e] + part[1][e]) + (part[2][e] + part[3][e]);
  __syncthreads();

  // residual + b2 + LayerNorm over V (x[] regs still hold the residual row)
  if (t < S) {
    float z[V];
    float mn = 0.f;
#pragma unroll
    for (int v = 0; v < V; ++v) {
      z[v] = x[v] + yfull[t * V + v] + b2[v];
      mn += z[v];
    }
    mn *= (1.f / V);
    float var = 0.f;
#pragma unroll
    for (int v = 0; v < V; ++v) {
      float d = z[v] - mn;
      var = fmaf(d, d, var);
    }
    const float inv = rsqrtf(var * (1.f / V) + EPSF);
#pragma unroll
    for (int v = 0; v < V; ++v)
      X1[(size_t)b * SV + t * V + v] = (z[v] - mn) * inv * lng[v] + lnb[v];
  }
}

// ---------------- K3: per-(b,h) attention -> O [B,59,189] ----------------
// lane = row. x row + q row in registers; QKV weights read as wave-uniform
// s_loads straight from global (never staged); only k/v rows + score rows in
// LDS. Lanes 59..63 duplicate row 58 (identical values -> benign LDS dup write).
__global__ __launch_bounds__(64) __attribute__((amdgpu_waves_per_eu(1, 8)))
void k_attn(
    const float* __restrict__ X1, const float* __restrict__ Wq, const float* __restrict__ Wk,
    const float* __restrict__ Wv, float* __restrict__ O) {
  __shared__ float ks[SV], vs[SV];
  __shared__ float ss[S * 61];  // score rows, odd stride
  const int lane = threadIdx.x;
  const int bh = blockIdx.x;
  const int b = bh / H;
  const int h = bh - b * H;
  const int row = lane < S ? lane : S - 1;

  float x[V];
  {
    const float* xr = X1 + (size_t)b * SV + row * V;
#pragma unroll
    for (int u = 0; u < V; ++u) x[u] = xr[u];
#pragma unroll
    for (int u = 0; u < V; ++u) asm volatile("" : "+v"(x[u]));  // pin: no remat
  }
  const float* wqh = Wq + h * V;
  const float* wkh = Wk + h * V;
  const float* wvh = Wv + h * V;
  float q[V];
  for (int d = 0; d < V; ++d) {
    float qa = 0.f, ka = 0.f, va = 0.f;
#pragma unroll
    for (int u = 0; u < V; ++u) {
      const float xv = x[u];
      qa = fmaf(xv, wqh[u * HD + d], qa);  // weight addr wave-uniform -> s_load
      ka = fmaf(xv, wkh[u * HD + d], ka);
      va = fmaf(xv, wvh[u * HD + d], va);
    }
    q[d] = qa;
    ks[row * V + d] = ka;   // lanes 59-63 rewrite row 58 with identical values
    vs[row * V + d] = va;
  }
  __syncthreads();

  if (lane < S) {
    const float rs = 0.21821789023599236f;  // 1/sqrt(21)
    float mx = -1e30f;
    for (int j = 0; j < S; ++j) {
      float acc = 0.f;
#pragma unroll
      for (int d = 0; d < V; ++d) acc = fmaf(q[d], ks[j * V + d], acc);
      acc *= rs;
      ss[lane * 61 + j] = acc;
      mx = fmaxf(mx, acc);
    }
    float sum = 0.f;
    for (int j = 0; j < S; ++j) {
      float e = __expf(ss[lane * 61 + j] - mx);
      ss[lane * 61 + j] = e;
      sum += e;
    }
    const float inv = __builtin_amdgcn_rcpf(sum);
    float o[V];
#pragma unroll
    for (int d = 0; d < V; ++d) o[d] = 0.f;
    for (int j = 0; j < S; ++j) {
      const float p = ss[lane * 61 + j];
#pragma unroll
      for (int d = 0; d < V; ++d) o[d] = fmaf(p, vs[j * V + d], o[d]);
    }
    float* op = O + (size_t)(b * S + lane) * HD + h * V;
#pragma unroll
    for (int d = 0; d < V; ++d) op[d] = o[d] * inv;
  }
}

// ---------------- K4: O @ Wo + residual + LN -> X2 ----------------
__global__ __launch_bounds__(128) void k_wo(
    const float* __restrict__ O, const float* __restrict__ Wo, const float* __restrict__ X1,
    const float* __restrict__ lng, const float* __restrict__ lnb, float* __restrict__ X2) {
  __shared__ float Ws[HD * V];
  __shared__ float yo[SV];
  const int t = threadIdx.x;
  const int b = blockIdx.x;
  for (int i = t; i < HD * V; i += 128) Ws[i] = Wo[i];
  __syncthreads();
  for (int i = t; i < SV; i += 128) {
    int l = i / V, v = i - l * V;
    const float* orow = O + (size_t)(b * S + l) * HD;
    float acc = 0;
#pragma unroll 9
    for (int m = 0; m < HD; ++m) acc = fmaf(orow[m], Ws[m * V + v], acc);
    yo[i] = acc;
  }
  __syncthreads();
  if (t < S) {
    float z[V];
    float m = 0;
#pragma unroll
    for (int v = 0; v < V; ++v) {
      z[v] = X1[b * SV + t * V + v] + yo[t * V + v];
      m += z[v];
    }
    m *= (1.f / V);
    float var = 0;
#pragma unroll
    for (int v = 0; v < V; ++v) {
      float d = z[v] - m;
      var = fmaf(d, d, var);
    }
    const float inv = rsqrtf(var * (1.f / V) + EPSF);
#pragma unroll
    for (int v = 0; v < V; ++v)
      X2[b * SV + t * V + v] = (z[v] - m) * inv * lng[v] + lnb[v];
  }
}

// ---------------- K5: head GEMM [B,1239]@[1239,800] + bias + silu + BN -> Hb ----------------
constexpr int BT = 8;    // batch rows per block
constexpr int NT = 200;  // output cols per block
__global__ __launch_bounds__(256) void k_f1(
    const float* __restrict__ X2, const float* __restrict__ Wf1, const float* __restrict__ bf1,
    const float* __restrict__ g2, const float* __restrict__ bb2, const float* __restrict__ m2,
    const float* __restrict__ v2, float* __restrict__ Hb) {
  __shared__ __align__(16) float Xs[BT * 1240];
  const int t = threadIdx.x;
  const int bbase = blockIdx.x * BT;
  const int nbase = blockIdx.y * NT;
  for (int i = t; i < BT * SV; i += 256) {
    int r = i / SV, f = i - r * SV;
    Xs[r * 1240 + f] = X2[(size_t)(bbase + r) * SV + f];
  }
  __syncthreads();
  if (t < NT) {
    const int n = nbase + t;
    float acc[BT];
#pragma unroll
    for (int r = 0; r < BT; ++r) acc[r] = 0.f;
    int f = 0;
    for (; f + 3 < SV; f += 4) {
      const float w0 = Wf1[(size_t)f * NH + n];
      const float w1 = Wf1[(size_t)(f + 1) * NH + n];
      const float w2 = Wf1[(size_t)(f + 2) * NH + n];
      const float w3 = Wf1[(size_t)(f + 3) * NH + n];
#pragma unroll
      for (int r = 0; r < BT; ++r) {
        const float4 x = *reinterpret_cast<const float4*>(&Xs[r * 1240 + f]);
        acc[r] = fmaf(x.x, w0, acc[r]);
        acc[r] = fmaf(x.y, w1, acc[r]);
        acc[r] = fmaf(x.z, w2, acc[r]);
        acc[r] = fmaf(x.w, w3, acc[r]);
      }
    }
    for (; f < SV; ++f) {
      const float w0 = Wf1[(size_t)f * NH + n];
#pragma unroll
      for (int r = 0; r < BT; ++r) acc[r] = fmaf(Xs[r * 1240 + f], w0, acc[r]);
    }
    const float sc = g2[n] * rsqrtf(v2[n] + EPSF);
    const float sh = bb2[n] - m2[n] * sc;
    const float bias = bf1[n];
#pragma unroll
    for (int r = 0; r < BT; ++r) {
      float hh = acc[r] + bias;
      hh = hh * sigm(hh);            // silu
      hh = fmaf(hh, sc, sh);         // BN2 (inference)
      Hb[(size_t)(bbase + r) * NH + n] = hh;
    }
  }
}

// ---------------- K6: relu(Hb@Wf2+bf2) @ Wf3 + bf3 -> out [B,2] ----------------
__global__ __launch_bounds__(64) void k_f23(
    const float* __restrict__ Hb, const float* __restrict__ Wf2, const float* __restrict__ bf2,
    const float* __restrict__ Wf3, const float* __restrict__ bf3, float* __restrict__ out) {
  __shared__ __align__(16) float hs[NH];
  const int t = threadIdx.x;
  const int b = blockIdx.x;
  for (int i = t; i < NH; i += 64) hs[i] = Hb[(size_t)b * NH + i];
  __syncthreads();
  float acc = bf2[t];
  for (int n = 0; n < NH; n += 4) {
    const float4 hv = *reinterpret_cast<const float4*>(&hs[n]);
    acc = fmaf(hv.x, Wf2[n * 64 + t], acc);
    acc = fmaf(hv.y, Wf2[(n + 1) * 64 + t], acc);
    acc = fmaf(hv.z, Wf2[(n + 2) * 64 + t], acc);
    acc = fmaf(hv.w, Wf2[(n + 3) * 64 + t], acc);
  }
  const float mid = fmaxf(acc, 0.f);
  float p0 = mid * Wf3[t * 2 + 0];
  float p1 = mid * Wf3[t * 2 + 1];
#pragma unroll
  for (int off = 32; off > 0; off >>= 1) {
    p0 += __shfl_down(p0, off);
    p1 += __shfl_down(p1, off);
  }
  if (t == 0) {
    out[b * 2 + 0] = p0 + bf3[0];
    out[b * 2 + 1] = p1 + bf3[1];
  }
}

}  // namespace

extern "C" void kernel_launch(void* const* d_in, const int* in_sizes, int n_in,
                              void* d_out, int out_size, void* d_ws, size_t ws_size,
                              hipStream_t stream) {
  const float* pep   = (const float*)d_in[0];
  const float* mhc   = (const float*)d_in[1];
  const float* W1    = (const float*)d_in[2];
  const float* b1    = (const float*)d_in[3];
  const float* Wd    = (const float*)d_in[4];
  const float* bd    = (const float*)d_in[5];
  const float* bn1_g = (const float*)d_in[6];
  const float* bn1_b = (const float*)d_in[7];
  const float* bn1_m = (const float*)d_in[8];
  const float* bn1_v = (const float*)d_in[9];
  const float* W2    = (const float*)d_in[10];
  const float* b2    = (const float*)d_in[11];
  const float* ln_g  = (const float*)d_in[12];
  const float* ln_b  = (const float*)d_in[13];
  const float* Wq    = (const float*)d_in[14];
  const float* Wk    = (const float*)d_in[15];
  const float* Wv    = (const float*)d_in[16];
  const float* Wo    = (const float*)d_in[17];
  const float* Wf1   = (const float*)d_in[18];
  const float* bf1   = (const float*)d_in[19];
  const float* bn2_g = (const float*)d_in[20];
  const float* bn2_b = (const float*)d_in[21];
  const float* bn2_m = (const float*)d_in[22];
  const float* bn2_v = (const float*)d_in[23];
  const float* Wf2   = (const float*)d_in[24];
  const float* bf2   = (const float*)d_in[25];
  const float* Wf3   = (const float*)d_in[26];
  const float* bf3   = (const float*)d_in[27];
  float* out = (float*)d_out;

  float* ws = (float*)d_ws;
  float* X1 = ws;                          // [B,59,21]
  float* X2 = X1 + (size_t)B * SV;         // [B,59,21]
  float* O  = X2 + (size_t)B * SV;         // [B,59,189]
  float* Hb = O + (size_t)B * S * HD;      // [B,800]
  float* Pk = Hb + (size_t)B * NH;         // [C,88] packed conv params

  k_pack<<<(C + 63) / 64, 64, 0, stream>>>(W1, b1, Wd, bd, bn1_g, bn1_b, bn1_m, bn1_v, W2, Pk);
  k_conv<<<B, 512, 0, stream>>>(pep, mhc, Pk, b2, ln_g, ln_b, X1);
  k_attn<<<B * H, 64, 0, stream>>>(X1, Wq, Wk, Wv, O);
  k_wo<<<B, 128, 0, stream>>>(O, Wo, X1, ln_g, ln_b, X2);
  dim3 g5(B / BT, NH / NT);
  k_f1<<<g5, 256, 0, stream>>>(X2, Wf1, bf1, bn2_g, bn2_b, bn2_m, bn2_v, Hb);
  k_f23<<<B, 64, 0, stream>>>(Hb, Wf2, bf2, Wf3, bf3, out);
}

// Round 8
// 613.712 us; speedup vs baseline: 1.7148x; 1.4961x over previous
//
#include <hip/hip_runtime.h>
#include <hip/hip_bf16.h>

namespace {

constexpr int B   = 1024;
constexpr int PEP = 15;
constexpr int MHCN = 44;
constexpr int S   = 59;    // sequence
constexpr int V   = 21;    // vocab / model dim
constexpr int C   = 3200;  // conv channels
constexpr int KW  = 9;     // depthwise kernel
constexpr int H   = 9;     // heads
constexpr int NH  = 800;
constexpr int SV  = S * V;   // 1239
constexpr int HD  = H * V;   // 189
constexpr float EPSF = 1e-5f;

typedef __attribute__((ext_vector_type(8))) short short8;   // 8 bf16 (4 VGPRs)
typedef __attribute__((ext_vector_type(4))) float f32x4;    // MFMA C/D frag

__device__ __forceinline__ float sigm(float x) {
  return __builtin_amdgcn_rcpf(1.f + __expf(-x));
}
__device__ __forceinline__ unsigned short f2bf(float f) {
  union { float f; unsigned u; } v; v.f = f;
  unsigned r = v.u + 0x7FFF + ((v.u >> 16) & 1);  // RNE
  return (unsigned short)(r >> 16);
}

// ---------------- K0: pack weights into MFMA B-fragment order (bf16) ----------------
// FB1: GLU-up B-frags. tile tau = ci*8 + tt (tt 0-3: 'a' rows, 4-7: 'g' rows).
//   FB1[tau*512 + lane*8 + j] = bf16(W1[row][k]), row = (tt<4? ci*64+tt*16 : C+ci*64+(tt-4)*16) + (lane&15),
//   k = (lane>>4)*8 + j, zero-pad k>=21.
// FB2: down-proj B-frags. sg = ci*4 + kt*2 + nt.
//   FB2[sg*512 + lane*8 + j] = bf16(W2[vcol][ch]), vcol = nt*16+(lane&15) (<21 else 0),
//   ch = ci*64 + kt*32 + (lane>>4)*8 + j.
// TAP[c*12 + 0..8] = Wd[c][k]*bn_sc; [9] = (bd-m)*sc + bb; [10,11] = 0.
__global__ void k_packW(const float* __restrict__ W1, const float* __restrict__ Wd,
                        const float* __restrict__ bd, const float* __restrict__ g,
                        const float* __restrict__ bb, const float* __restrict__ m,
                        const float* __restrict__ vv, const float* __restrict__ W2,
                        unsigned short* __restrict__ FB1, unsigned short* __restrict__ FB2,
                        float* __restrict__ TAP) {
  int id = blockIdx.x * 256 + threadIdx.x;
  if (id < 400 * 64) {
    int tau = id >> 6, l = id & 63;
    int ci = tau >> 3, tt = tau & 7;
    int lr = l & 15, lg = l >> 4;
    int row = (tt < 4) ? (ci * 64 + tt * 16 + lr) : (C + ci * 64 + (tt - 4) * 16 + lr);
    for (int j = 0; j < 8; ++j) {
      int k = lg * 8 + j;
      float val = (k < V) ? W1[row * V + k] : 0.f;
      FB1[(size_t)tau * 512 + l * 8 + j] = f2bf(val);
    }
  } else if (id < 400 * 64 + 200 * 64) {
    int id2 = id - 400 * 64;
    int sg = id2 >> 6, l = id2 & 63;
    int ci = sg >> 2, rem = sg & 3, kt = rem >> 1, nt = rem & 1;
    int lr = l & 15, lg = l >> 4;
    int vc = nt * 16 + lr;
    for (int j = 0; j < 8; ++j) {
      int ch = ci * 64 + kt * 32 + lg * 8 + j;
      float val = (vc < V) ? W2[(size_t)vc * C + ch] : 0.f;
      FB2[(size_t)sg * 512 + l * 8 + j] = f2bf(val);
    }
  } else {
    int c = id - 400 * 64 - 200 * 64;
    if (c < C) {
      float sc = g[c] * rsqrtf(vv[c] + EPSF);
      for (int k = 0; k < KW; ++k) TAP[c * 12 + k] = Wd[c * KW + k] * sc;
      TAP[c * 12 + 9]  = (bd[c] - m[c]) * sc + bb[c];
      TAP[c * 12 + 10] = 0.f;
      TAP[c * 12 + 11] = 0.f;
    }
  }
}

// ---------------- K2: MFMA conv module + residual + LN -> X1 ----------------
// Block = 1 batch, 4 waves = 4 M-tiles of 16 positions (M=64, pos>=59 padded).
// Per 64-channel chunk: 8 GLU MFMAs -> GLU epilogue -> glbuf (shared LDS) ->
// depthwise conv (wave w owns positions w*16..+15, lane = channel) -> Sb bf16
// (wave-private, wave-synchronous) -> 4 down-proj MFMAs into persistent C-frags.
__global__ __launch_bounds__(256) void k_conv(
    const float* __restrict__ pep, const float* __restrict__ mhc,
    const unsigned short* __restrict__ FB1, const unsigned short* __restrict__ FB2,
    const float* __restrict__ TAP, const float* __restrict__ b1,
    const float* __restrict__ b2, const float* __restrict__ lng,
    const float* __restrict__ lnb, float* __restrict__ X1) {
  __shared__ __align__(16) unsigned short Xbf[64 * 40];   // [row][col] bf16, stride 40
  __shared__ float glbuf[64 * 73];                        // [ch][4+pos] f32, stride 73 (banks)
  __shared__ __align__(16) unsigned short Sbuf[4][16 * 72]; // per-wave [pos-in-tile][ch] bf16
  __shared__ float yfull[SV];
  const int t = threadIdx.x;
  const int b = blockIdx.x;
  const int lane = t & 63;
  const int w = t >> 6;        // wave id = M-tile
  const int lr = lane & 15;
  const int lg = lane >> 4;

  // ---- stage: zero glbuf left halo; X -> bf16 LDS (rows>=59 and cols>=21 zero) ----
  for (int i = t; i < 64 * 4; i += 256) glbuf[(i >> 2) * 73 + (i & 3)] = 0.f;
  {
    const int row = t >> 2, q = t & 3;
    const float* xr = (row < PEP) ? pep + ((size_t)b * PEP + row) * V
                    : (row < S)   ? mhc + ((size_t)b * MHCN + (row - PEP)) * V
                                  : nullptr;
#pragma unroll
    for (int i2 = 0; i2 < 5; ++i2) {
      int c0 = q * 10 + 2 * i2;
      float f0 = (xr && c0 < V) ? xr[c0] : 0.f;
      float f1 = (xr && c0 + 1 < V) ? xr[c0 + 1] : 0.f;
      unsigned pkv = (unsigned)f2bf(f0) | ((unsigned)f2bf(f1) << 16);
      *reinterpret_cast<unsigned*>(&Xbf[row * 40 + c0]) = pkv;
    }
  }
  __syncthreads();

  // persistent A-frag (X rows of this wave's M-tile) + down-proj accumulators
  short8 ax = *reinterpret_cast<const short8*>(&Xbf[(w * 16 + lr) * 40 + lg * 8]);
  f32x4 acc2[2];
  acc2[0] = (f32x4){0.f, 0.f, 0.f, 0.f};
  acc2[1] = (f32x4){0.f, 0.f, 0.f, 0.f};
  const int mypos = w * 16 + lg * 4;  // D-row base for this lane

  for (int ci = 0; ci < C / 64; ++ci) {
    const unsigned short* fb1 = FB1 + (size_t)ci * 8 * 512;
    f32x4 ga[4], gg[4];
#pragma unroll
    for (int tt = 0; tt < 4; ++tt) {
      short8 bf = *reinterpret_cast<const short8*>(fb1 + tt * 512 + lane * 8);
      ga[tt] = __builtin_amdgcn_mfma_f32_16x16x32_bf16(ax, bf, (f32x4){0.f, 0.f, 0.f, 0.f}, 0, 0, 0);
    }
#pragma unroll
    for (int tt = 0; tt < 4; ++tt) {
      short8 bf = *reinterpret_cast<const short8*>(fb1 + (4 + tt) * 512 + lane * 8);
      gg[tt] = __builtin_amdgcn_mfma_f32_16x16x32_bf16(ax, bf, (f32x4){0.f, 0.f, 0.f, 0.f}, 0, 0, 0);
    }
    // ---- GLU epilogue: gl = (a+ba)*sigm(g+bg); rows pos>=59 forced 0 (conv halo) ----
#pragma unroll
    for (int tt = 0; tt < 4; ++tt) {
      const int ch = ci * 64 + tt * 16 + lr;
      const float ba = b1[ch], bg = b1[C + ch];
#pragma unroll
      for (int r = 0; r < 4; ++r) {
        const int pos = mypos + r;
        float av = ga[tt][r] + ba;
        float gv = gg[tt][r] + bg;
        float gl = av * sigm(gv);
        glbuf[(tt * 16 + lr) * 73 + 4 + pos] = (pos < S) ? gl : 0.f;
      }
    }
    __syncthreads();  // bar1: glbuf complete
    // ---- depthwise conv + shift + SiLU -> Sb bf16 (wave-private) ----
    {
      const float* tp = TAP + (size_t)(ci * 64 + lane) * 12;
      const float4 t0 = *reinterpret_cast<const float4*>(tp);
      const float4 t1 = *reinterpret_cast<const float4*>(tp + 4);
      const float4 t2 = *reinterpret_cast<const float4*>(tp + 8);
      const float tap[9] = {t0.x, t0.y, t0.z, t0.w, t1.x, t1.y, t1.z, t1.w, t2.x};
      const float sh = t2.y;
      float gv[24];
#pragma unroll
      for (int i2 = 0; i2 < 24; ++i2) gv[i2] = glbuf[lane * 73 + w * 16 + i2];
      // gv[i] = gl[pos = w*16 + i - 4]
#pragma unroll
      for (int i2 = 0; i2 < 16; ++i2) {
        float a = sh;
#pragma unroll
        for (int k = 0; k < KW; ++k) a = fmaf(gv[i2 + k], tap[k], a);
        const float sb = a * sigm(a);
        const int pos = w * 16 + i2;
        Sbuf[w][i2 * 72 + lane] = (pos < S) ? f2bf(sb) : (unsigned short)0;
      }
    }
    // ---- down-proj MFMAs (A2 from own Sbuf, wave-synchronous) ----
    const unsigned short* fb2 = FB2 + (size_t)ci * 4 * 512;
#pragma unroll
    for (int kt = 0; kt < 2; ++kt) {
      short8 a2f = *reinterpret_cast<const short8*>(&Sbuf[w][lr * 72 + kt * 32 + lg * 8]);
#pragma unroll
      for (int nt = 0; nt < 2; ++nt) {
        short8 b2f = *reinterpret_cast<const short8*>(fb2 + (kt * 2 + nt) * 512 + lane * 8);
        acc2[nt] = __builtin_amdgcn_mfma_f32_16x16x32_bf16(a2f, b2f, acc2[nt], 0, 0, 0);
      }
    }
    __syncthreads();  // bar2: conv reads of glbuf done -> next chunk may overwrite
  }

  // ---- scatter down-proj result ----
#pragma unroll
  for (int nt = 0; nt < 2; ++nt) {
#pragma unroll
    for (int r = 0; r < 4; ++r) {
      const int pos = mypos + r, vc = nt * 16 + lr;
      if (pos < S && vc < V) yfull[pos * V + vc] = acc2[nt][r];
    }
  }
  __syncthreads();

  // ---- residual + b2 + LayerNorm (reload residual row fp32 from global) ----
  if (t < S) {
    const float* xr = (t < PEP) ? pep + ((size_t)b * PEP + t) * V
                                : mhc + ((size_t)b * MHCN + (t - PEP)) * V;
    float z[V];
    float mn = 0.f;
#pragma unroll
    for (int v = 0; v < V; ++v) {
      z[v] = xr[v] + yfull[t * V + v] + b2[v];
      mn += z[v];
    }
    mn *= (1.f / V);
    float var = 0.f;
#pragma unroll
    for (int v = 0; v < V; ++v) {
      float d = z[v] - mn;
      var = fmaf(d, d, var);
    }
    const float inv = rsqrtf(var * (1.f / V) + EPSF);
#pragma unroll
    for (int v = 0; v < V; ++v)
      X1[(size_t)b * SV + t * V + v] = (z[v] - mn) * inv * lng[v] + lnb[v];
  }
}

// ---------------- K3: per-(b,h) attention -> O [B,59,189] ----------------
__global__ __launch_bounds__(64) __attribute__((amdgpu_waves_per_eu(1, 8)))
void k_attn(
    const float* __restrict__ X1, const float* __restrict__ Wq, const float* __restrict__ Wk,
    const float* __restrict__ Wv, float* __restrict__ O) {
  __shared__ float ks[SV], vs[SV];
  __shared__ float ss[S * 61];  // score rows, odd stride
  const int lane = threadIdx.x;
  const int bh = blockIdx.x;
  const int b = bh / H;
  const int h = bh - b * H;
  const int row = lane < S ? lane : S - 1;

  float x[V];
  {
    const float* xr = X1 + (size_t)b * SV + row * V;
#pragma unroll
    for (int u = 0; u < V; ++u) x[u] = xr[u];
#pragma unroll
    for (int u = 0; u < V; ++u) asm volatile("" : "+v"(x[u]));  // pin: no remat
  }
  const float* wqh = Wq + h * V;
  const float* wkh = Wk + h * V;
  const float* wvh = Wv + h * V;
  float q[V];
  for (int d = 0; d < V; ++d) {
    float qa = 0.f, ka = 0.f, va = 0.f;
#pragma unroll
    for (int u = 0; u < V; ++u) {
      const float xv = x[u];
      qa = fmaf(xv, wqh[u * HD + d], qa);  // weight addr wave-uniform -> s_load
      ka = fmaf(xv, wkh[u * HD + d], ka);
      va = fmaf(xv, wvh[u * HD + d], va);
    }
    q[d] = qa;
    ks[row * V + d] = ka;
    vs[row * V + d] = va;
  }
  __syncthreads();

  if (lane < S) {
    const float rs = 0.21821789023599236f;  // 1/sqrt(21)
    float mx = -1e30f;
    for (int j = 0; j < S; ++j) {
      float acc = 0.f;
#pragma unroll
      for (int d = 0; d < V; ++d) acc = fmaf(q[d], ks[j * V + d], acc);
      acc *= rs;
      ss[lane * 61 + j] = acc;
      mx = fmaxf(mx, acc);
    }
    float sum = 0.f;
    for (int j = 0; j < S; ++j) {
      float e = __expf(ss[lane * 61 + j] - mx);
      ss[lane * 61 + j] = e;
      sum += e;
    }
    const float inv = __builtin_amdgcn_rcpf(sum);
    float o[V];
#pragma unroll
    for (int d = 0; d < V; ++d) o[d] = 0.f;
    for (int j = 0; j < S; ++j) {
      const float p = ss[lane * 61 + j];
#pragma unroll
      for (int d = 0; d < V; ++d) o[d] = fmaf(p, vs[j * V + d], o[d]);
    }
    float* op = O + (size_t)(b * S + lane) * HD + h * V;
#pragma unroll
    for (int d = 0; d < V; ++d) op[d] = o[d] * inv;
  }
}

// ---------------- K4: O @ Wo + residual + LN -> X2 ----------------
__global__ __launch_bounds__(128) void k_wo(
    const float* __restrict__ O, const float* __restrict__ Wo, const float* __restrict__ X1,
    const float* __restrict__ lng, const float* __restrict__ lnb, float* __restrict__ X2) {
  __shared__ float Ws[HD * V];
  __shared__ float yo[SV];
  const int t = threadIdx.x;
  const int b = blockIdx.x;
  for (int i = t; i < HD * V; i += 128) Ws[i] = Wo[i];
  __syncthreads();
  for (int i = t; i < SV; i += 128) {
    int l = i / V, v = i - l * V;
    const float* orow = O + (size_t)(b * S + l) * HD;
    float acc = 0;
#pragma unroll 9
    for (int m = 0; m < HD; ++m) acc = fmaf(orow[m], Ws[m * V + v], acc);
    yo[i] = acc;
  }
  __syncthreads();
  if (t < S) {
    float z[V];
    float m = 0;
#pragma unroll
    for (int v = 0; v < V; ++v) {
      z[v] = X1[b * SV + t * V + v] + yo[t * V + v];
      m += z[v];
    }
    m *= (1.f / V);
    float var = 0;
#pragma unroll
    for (int v = 0; v < V; ++v) {
      float d = z[v] - m;
      var = fmaf(d, d, var);
    }
    const float inv = rsqrtf(var * (1.f / V) + EPSF);
#pragma unroll
    for (int v = 0; v < V; ++v)
      X2[b * SV + t * V + v] = (z[v] - m) * inv * lng[v] + lnb[v];
  }
}

// ---------------- K5: head GEMM [B,1239]@[1239,800] + bias + silu + BN -> Hb ----------------
constexpr int BT = 8;    // batch rows per block
constexpr int NT = 200;  // output cols per block
__global__ __launch_bounds__(256) void k_f1(
    const float* __restrict__ X2, const float* __restrict__ Wf1, const float* __restrict__ bf1,
    const float* __restrict__ g2, const float* __restrict__ bb2, const float* __restrict__ m2,
    const float* __restrict__ v2, float* __restrict__ Hb) {
  __shared__ __align__(16) float Xs[BT * 1240];
  const int t = threadIdx.x;
  const int bbase = blockIdx.x * BT;
  const int nbase = blockIdx.y * NT;
  for (int i = t; i < BT * SV; i += 256) {
    int r = i / SV, f = i - r * SV;
    Xs[r * 1240 + f] = X2[(size_t)(bbase + r) * SV + f];
  }
  __syncthreads();
  if (t < NT) {
    const int n = nbase + t;
    float acc[BT];
#pragma unroll
    for (int r = 0; r < BT; ++r) acc[r] = 0.f;
    int f = 0;
    for (; f + 3 < SV; f += 4) {
      const float w0 = Wf1[(size_t)f * NH + n];
      const float w1 = Wf1[(size_t)(f + 1) * NH + n];
      const float w2 = Wf1[(size_t)(f + 2) * NH + n];
      const float w3 = Wf1[(size_t)(f + 3) * NH + n];
#pragma unroll
      for (int r = 0; r < BT; ++r) {
        const float4 x = *reinterpret_cast<const float4*>(&Xs[r * 1240 + f]);
        acc[r] = fmaf(x.x, w0, acc[r]);
        acc[r] = fmaf(x.y, w1, acc[r]);
        acc[r] = fmaf(x.z, w2, acc[r]);
        acc[r] = fmaf(x.w, w3, acc[r]);
      }
    }
    for (; f < SV; ++f) {
      const float w0 = Wf1[(size_t)f * NH + n];
#pragma unroll
      for (int r = 0; r < BT; ++r) acc[r] = fmaf(Xs[r * 1240 + f], w0, acc[r]);
    }
    const float sc = g2[n] * rsqrtf(v2[n] + EPSF);
    const float sh = bb2[n] - m2[n] * sc;
    const float bias = bf1[n];
#pragma unroll
    for (int r = 0; r < BT; ++r) {
      float hh = acc[r] + bias;
      hh = hh * sigm(hh);
      hh = fmaf(hh, sc, sh);
      Hb[(size_t)(bbase + r) * NH + n] = hh;
    }
  }
}

// ---------------- K6: relu(Hb@Wf2+bf2) @ Wf3 + bf3 -> out [B,2] ----------------
__global__ __launch_bounds__(64) void k_f23(
    const float* __restrict__ Hb, const float* __restrict__ Wf2, const float* __restrict__ bf2,
    const float* __restrict__ Wf3, const float* __restrict__ bf3, float* __restrict__ out) {
  __shared__ __align__(16) float hs[NH];
  const int t = threadIdx.x;
  const int b = blockIdx.x;
  for (int i = t; i < NH; i += 64) hs[i] = Hb[(size_t)b * NH + i];
  __syncthreads();
  float acc = bf2[t];
  for (int n = 0; n < NH; n += 4) {
    const float4 hv = *reinterpret_cast<const float4*>(&hs[n]);
    acc = fmaf(hv.x, Wf2[n * 64 + t], acc);
    acc = fmaf(hv.y, Wf2[(n + 1) * 64 + t], acc);
    acc = fmaf(hv.z, Wf2[(n + 2) * 64 + t], acc);
    acc = fmaf(hv.w, Wf2[(n + 3) * 64 + t], acc);
  }
  const float mid = fmaxf(acc, 0.f);
  float p0 = mid * Wf3[t * 2 + 0];
  float p1 = mid * Wf3[t * 2 + 1];
#pragma unroll
  for (int off = 32; off > 0; off >>= 1) {
    p0 += __shfl_down(p0, off);
    p1 += __shfl_down(p1, off);
  }
  if (t == 0) {
    out[b * 2 + 0] = p0 + bf3[0];
    out[b * 2 + 1] = p1 + bf3[1];
  }
}

}  // namespace

extern "C" void kernel_launch(void* const* d_in, const int* in_sizes, int n_in,
                              void* d_out, int out_size, void* d_ws, size_t ws_size,
                              hipStream_t stream) {
  const float* pep   = (const float*)d_in[0];
  const float* mhc   = (const float*)d_in[1];
  const float* W1    = (const float*)d_in[2];
  const float* b1    = (const float*)d_in[3];
  const float* Wd    = (const float*)d_in[4];
  const float* bd    = (const float*)d_in[5];
  const float* bn1_g = (const float*)d_in[6];
  const float* bn1_b = (const float*)d_in[7];
  const float* bn1_m = (const float*)d_in[8];
  const float* bn1_v = (const float*)d_in[9];
  const float* W2    = (const float*)d_in[10];
  const float* b2    = (const float*)d_in[11];
  const float* ln_g  = (const float*)d_in[12];
  const float* ln_b  = (const float*)d_in[13];
  const float* Wq    = (const float*)d_in[14];
  const float* Wk    = (const float*)d_in[15];
  const float* Wv    = (const float*)d_in[16];
  const float* Wo    = (const float*)d_in[17];
  const float* Wf1   = (const float*)d_in[18];
  const float* bf1   = (const float*)d_in[19];
  const float* bn2_g = (const float*)d_in[20];
  const float* bn2_b = (const float*)d_in[21];
  const float* bn2_m = (const float*)d_in[22];
  const float* bn2_v = (const float*)d_in[23];
  const float* Wf2   = (const float*)d_in[24];
  const float* bf2   = (const float*)d_in[25];
  const float* Wf3   = (const float*)d_in[26];
  const float* bf3   = (const float*)d_in[27];
  float* out = (float*)d_out;

  float* ws = (float*)d_ws;
  float* X1 = ws;                               // [B,59,21]
  float* X2 = X1 + (size_t)B * SV;              // [B,59,21]
  float* O  = X2 + (size_t)B * SV;              // [B,59,189]
  float* Hb = O + (size_t)B * S * HD;           // [B,800]
  float* TAP = Hb + (size_t)B * NH;             // [C,12] f32
  unsigned short* FB1 = (unsigned short*)(TAP + (size_t)C * 12);  // 400 tiles x 512 bf16
  unsigned short* FB2 = FB1 + (size_t)400 * 512;                  // 200 tiles x 512 bf16

  k_packW<<<163, 256, 0, stream>>>(W1, Wd, bd, bn1_g, bn1_b, bn1_m, bn1_v, W2, FB1, FB2, TAP);
  k_conv<<<B, 256, 0, stream>>>(pep, mhc, FB1, FB2, TAP, b1, b2, ln_g, ln_b, X1);
  k_attn<<<B * H, 64, 0, stream>>>(X1, Wq, Wk, Wv, O);
  k_wo<<<B, 128, 0, stream>>>(O, Wo, X1, ln_g, ln_b, X2);
  dim3 g5(B / BT, NH / NT);
  k_f1<<<g5, 256, 0, stream>>>(X2, Wf1, bf1, bn2_g, bn2_b, bn2_m, bn2_v, Hb);
  k_f23<<<B, 64, 0, stream>>>(Hb, Wf2, bf2, Wf3, bf3, out);
}

// Round 9
// 377.117 us; speedup vs baseline: 2.7907x; 1.6274x over previous
//
#include <hip/hip_runtime.h>
#include <hip/hip_bf16.h>

namespace {

constexpr int B   = 1024;
constexpr int PEP = 15;
constexpr int MHCN = 44;
constexpr int S   = 59;    // sequence
constexpr int V   = 21;    // vocab / model dim
constexpr int C   = 3200;  // conv channels
constexpr int KW  = 9;     // depthwise kernel
constexpr int H   = 9;     // heads
constexpr int NH  = 800;
constexpr int SV  = S * V;   // 1239
constexpr int HD  = H * V;   // 189
constexpr float EPSF = 1e-5f;

typedef __attribute__((ext_vector_type(8))) short short8;   // 8 bf16 (4 VGPRs)
typedef __attribute__((ext_vector_type(4))) float f32x4;    // MFMA C/D frag

__device__ __forceinline__ float sigm(float x) {
  return __builtin_amdgcn_rcpf(1.f + __expf(-x));
}
__device__ __forceinline__ unsigned short f2bf(float f) {
  union { float f; unsigned u; } v; v.f = f;
  unsigned r = v.u + 0x7FFF + ((v.u >> 16) & 1);  // RNE
  return (unsigned short)(r >> 16);
}

// ---------------- K0: pack all weights into MFMA B-fragment order (bf16) ----------------
// Verified frag convention (R8): mfma(Afrag,Bfrag)=A@B^T with A[m=lr][k=lg*8+j],
// B[n=lr][k=lg*8+j], D[row=lg*4+reg][col=lr].
// FB1 (conv GLU-up), FB2 (conv down-proj), FQKV (attn q/k/v), FWo (attn out), TAP (dw taps).
constexpr int PKS = 88;
__global__ void k_packW(const float* __restrict__ W1, const float* __restrict__ Wd,
                        const float* __restrict__ bd, const float* __restrict__ g,
                        const float* __restrict__ bb, const float* __restrict__ m,
                        const float* __restrict__ vv, const float* __restrict__ W2,
                        const float* __restrict__ Wq, const float* __restrict__ Wk,
                        const float* __restrict__ Wv, const float* __restrict__ Wo,
                        unsigned short* __restrict__ FB1, unsigned short* __restrict__ FB2,
                        unsigned short* __restrict__ FQKV, unsigned short* __restrict__ FWo,
                        float* __restrict__ TAP) {
  int id = blockIdx.x * 256 + threadIdx.x;
  if (id < 400 * 64) {                       // FB1
    int tau = id >> 6, l = id & 63;
    int ci = tau >> 3, tt = tau & 7;
    int lr = l & 15, lg = l >> 4;
    int row = (tt < 4) ? (ci * 64 + tt * 16 + lr) : (C + ci * 64 + (tt - 4) * 16 + lr);
    for (int j = 0; j < 8; ++j) {
      int k = lg * 8 + j;
      float val = (k < V) ? W1[row * V + k] : 0.f;
      FB1[(size_t)tau * 512 + l * 8 + j] = f2bf(val);
    }
  } else if (id < 38400) {                   // FB2
    int id2 = id - 25600;
    int sg = id2 >> 6, l = id2 & 63;
    int ci = sg >> 2, rem = sg & 3, kt = rem >> 1, nt = rem & 1;
    int lr = l & 15, lg = l >> 4;
    int vc = nt * 16 + lr;
    for (int j = 0; j < 8; ++j) {
      int ch = ci * 64 + kt * 32 + lg * 8 + j;
      float val = (vc < V) ? W2[(size_t)vc * C + ch] : 0.f;
      FB2[(size_t)sg * 512 + l * 8 + j] = f2bf(val);
    }
  } else if (id < 41856) {                   // FQKV: 9h x 3mat x 2nt tiles
    int id2 = id - 38400;
    int tile = id2 >> 6, l = id2 & 63;
    int h = tile / 6, rem = tile - h * 6;
    int mat = rem >> 1, nt = rem & 1;
    int lr = l & 15, kg = l >> 4;
    int dcol = nt * 16 + lr;
    const float* W = (mat == 0) ? Wq : (mat == 1) ? Wk : Wv;
    const float scale = (mat == 0) ? 0.21821789023599236f : 1.f;  // 1/sqrt(21) into Q
    for (int j = 0; j < 8; ++j) {
      int u = kg * 8 + j;
      float val = (u < V && dcol < V) ? W[u * HD + h * V + dcol] * scale : 0.f;
      FQKV[(size_t)tile * 512 + l * 8 + j] = f2bf(val);
    }
  } else if (id < 43008) {                   // FWo: 9h x 2nt tiles, k = head-dim d (pad 32)
    int id2 = id - 41856;
    int tile = id2 >> 6, l = id2 & 63;
    int h = tile >> 1, nt = tile & 1;
    int lr = l & 15, kg = l >> 4;
    int vcol = nt * 16 + lr;
    for (int j = 0; j < 8; ++j) {
      int d = kg * 8 + j;
      float val = (d < V && vcol < V) ? Wo[(h * V + d) * V + vcol] : 0.f;
      FWo[(size_t)tile * 512 + l * 8 + j] = f2bf(val);
    }
  } else {                                   // TAP
    int c = id - 43008;
    if (c < C) {
      float sc = g[c] * rsqrtf(vv[c] + EPSF);
      for (int k = 0; k < KW; ++k) TAP[c * 12 + k] = Wd[c * KW + k] * sc;
      TAP[c * 12 + 9]  = (bd[c] - m[c]) * sc + bb[c];
      TAP[c * 12 + 10] = 0.f;
      TAP[c * 12 + 11] = 0.f;
    }
  }
}

// ---------------- K2: MFMA conv module + residual + LN -> X1 (unchanged from R8) ----------------
__global__ __launch_bounds__(256) void k_conv(
    const float* __restrict__ pep, const float* __restrict__ mhc,
    const unsigned short* __restrict__ FB1, const unsigned short* __restrict__ FB2,
    const float* __restrict__ TAP, const float* __restrict__ b1,
    const float* __restrict__ b2, const float* __restrict__ lng,
    const float* __restrict__ lnb, float* __restrict__ X1) {
  __shared__ __align__(16) unsigned short Xbf[64 * 40];
  __shared__ float glbuf[64 * 73];
  __shared__ __align__(16) unsigned short Sbuf[4][16 * 72];
  __shared__ float yfull[SV];
  const int t = threadIdx.x;
  const int b = blockIdx.x;
  const int lane = t & 63;
  const int w = t >> 6;
  const int lr = lane & 15;
  const int lg = lane >> 4;

  for (int i = t; i < 64 * 4; i += 256) glbuf[(i >> 2) * 73 + (i & 3)] = 0.f;
  {
    const int row = t >> 2, q = t & 3;
    const float* xr = (row < PEP) ? pep + ((size_t)b * PEP + row) * V
                    : (row < S)   ? mhc + ((size_t)b * MHCN + (row - PEP)) * V
                                  : nullptr;
#pragma unroll
    for (int i2 = 0; i2 < 5; ++i2) {
      int c0 = q * 10 + 2 * i2;
      float f0 = (xr && c0 < V) ? xr[c0] : 0.f;
      float f1 = (xr && c0 + 1 < V) ? xr[c0 + 1] : 0.f;
      unsigned pkv = (unsigned)f2bf(f0) | ((unsigned)f2bf(f1) << 16);
      *reinterpret_cast<unsigned*>(&Xbf[row * 40 + c0]) = pkv;
    }
  }
  __syncthreads();

  short8 ax = *reinterpret_cast<const short8*>(&Xbf[(w * 16 + lr) * 40 + lg * 8]);
  f32x4 acc2[2];
  acc2[0] = (f32x4){0.f, 0.f, 0.f, 0.f};
  acc2[1] = (f32x4){0.f, 0.f, 0.f, 0.f};
  const int mypos = w * 16 + lg * 4;

  for (int ci = 0; ci < C / 64; ++ci) {
    const unsigned short* fb1 = FB1 + (size_t)ci * 8 * 512;
    f32x4 ga[4], gg[4];
#pragma unroll
    for (int tt = 0; tt < 4; ++tt) {
      short8 bf = *reinterpret_cast<const short8*>(fb1 + tt * 512 + lane * 8);
      ga[tt] = __builtin_amdgcn_mfma_f32_16x16x32_bf16(ax, bf, (f32x4){0.f, 0.f, 0.f, 0.f}, 0, 0, 0);
    }
#pragma unroll
    for (int tt = 0; tt < 4; ++tt) {
      short8 bf = *reinterpret_cast<const short8*>(fb1 + (4 + tt) * 512 + lane * 8);
      gg[tt] = __builtin_amdgcn_mfma_f32_16x16x32_bf16(ax, bf, (f32x4){0.f, 0.f, 0.f, 0.f}, 0, 0, 0);
    }
#pragma unroll
    for (int tt = 0; tt < 4; ++tt) {
      const int ch = ci * 64 + tt * 16 + lr;
      const float ba = b1[ch], bg = b1[C + ch];
#pragma unroll
      for (int r = 0; r < 4; ++r) {
        const int pos = mypos + r;
        float av = ga[tt][r] + ba;
        float gv = gg[tt][r] + bg;
        float gl = av * sigm(gv);
        glbuf[(tt * 16 + lr) * 73 + 4 + pos] = (pos < S) ? gl : 0.f;
      }
    }
    __syncthreads();
    {
      const float* tp = TAP + (size_t)(ci * 64 + lane) * 12;
      const float4 t0 = *reinterpret_cast<const float4*>(tp);
      const float4 t1 = *reinterpret_cast<const float4*>(tp + 4);
      const float4 t2 = *reinterpret_cast<const float4*>(tp + 8);
      const float tap[9] = {t0.x, t0.y, t0.z, t0.w, t1.x, t1.y, t1.z, t1.w, t2.x};
      const float sh = t2.y;
      float gv[24];
#pragma unroll
      for (int i2 = 0; i2 < 24; ++i2) gv[i2] = glbuf[lane * 73 + w * 16 + i2];
#pragma unroll
      for (int i2 = 0; i2 < 16; ++i2) {
        float a = sh;
#pragma unroll
        for (int k = 0; k < KW; ++k) a = fmaf(gv[i2 + k], tap[k], a);
        const float sb = a * sigm(a);
        const int pos = w * 16 + i2;
        Sbuf[w][i2 * 72 + lane] = (pos < S) ? f2bf(sb) : (unsigned short)0;
      }
    }
    const unsigned short* fb2 = FB2 + (size_t)ci * 4 * 512;
#pragma unroll
    for (int kt = 0; kt < 2; ++kt) {
      short8 a2f = *reinterpret_cast<const short8*>(&Sbuf[w][lr * 72 + kt * 32 + lg * 8]);
#pragma unroll
      for (int nt = 0; nt < 2; ++nt) {
        short8 b2f = *reinterpret_cast<const short8*>(fb2 + (kt * 2 + nt) * 512 + lane * 8);
        acc2[nt] = __builtin_amdgcn_mfma_f32_16x16x32_bf16(a2f, b2f, acc2[nt], 0, 0, 0);
      }
    }
    __syncthreads();
  }

#pragma unroll
  for (int nt = 0; nt < 2; ++nt) {
#pragma unroll
    for (int r = 0; r < 4; ++r) {
      const int pos = mypos + r, vc = nt * 16 + lr;
      if (pos < S && vc < V) yfull[pos * V + vc] = acc2[nt][r];
    }
  }
  __syncthreads();

  if (t < S) {
    const float* xr = (t < PEP) ? pep + ((size_t)b * PEP + t) * V
                                : mhc + ((size_t)b * MHCN + (t - PEP)) * V;
    float z[V];
    float mn = 0.f;
#pragma unroll
    for (int v = 0; v < V; ++v) {
      z[v] = xr[v] + yfull[t * V + v] + b2[v];
      mn += z[v];
    }
    mn *= (1.f / V);
    float var = 0.f;
#pragma unroll
    for (int v = 0; v < V; ++v) {
      float d = z[v] - mn;
      var = fmaf(d, d, var);
    }
    const float inv = rsqrtf(var * (1.f / V) + EPSF);
#pragma unroll
    for (int v = 0; v < V; ++v)
      X1[(size_t)b * SV + t * V + v] = (z[v] - mn) * inv * lng[v] + lnb[v];
  }
}

// ---------------- K3: fused MFMA attention + Wo + residual + LN -> X2 ----------------
// Block = 1 batch, 4 waves. Wave w owns query/pos tile w (rows w*16..w*16+15).
// Per head: QKV proj (6 mfma) -> S^T = mfma(Kfrag, Qfrag) (4) -> in-lane softmax
// (col i = lane&15 fixed) -> Pt/Oh wave-private LDS round-trips -> PV (4) ->
// Wo accumulate (2) into persistent C-frags. Epilogue: residual + LN.
__global__ __launch_bounds__(256) void k_attn(
    const float* __restrict__ X1, const unsigned short* __restrict__ FQKV,
    const unsigned short* __restrict__ FWo, const float* __restrict__ lng,
    const float* __restrict__ lnb, float* __restrict__ X2) {
  __shared__ float X1f[64 * 21];                          // f32 input + residual
  __shared__ __align__(16) unsigned short Qb[64 * 40];    // [pos][d] bf16
  __shared__ __align__(16) unsigned short Kb[64 * 40];    // [pos][d]
  __shared__ __align__(16) unsigned short Vt[32 * 72];    // [d][pos]  (V transposed)
  __shared__ __align__(16) unsigned short Pt[64 * 72];    // [i][j]    (P transposed)
  __shared__ __align__(16) unsigned short Oh[64 * 40];    // [i][d]    per-head O
  const int t = threadIdx.x;
  const int b = blockIdx.x;
  const int lane = t & 63;
  const int w = t >> 6;
  const int lr = lane & 15;
  const int lg = lane >> 4;

  for (int i = t; i < 64 * 21; i += 256)
    X1f[i] = (i < SV) ? X1[(size_t)b * SV + i] : 0.f;
  __syncthreads();

  // persistent A-frag of X rows (this wave's pos tile)
  short8 ax;
  {
    const int rowi = w * 16 + lr;
#pragma unroll
    for (int j = 0; j < 8; ++j) {
      int col = lg * 8 + j;
      ax[j] = (short)((col < V) ? f2bf(X1f[rowi * 21 + col]) : (unsigned short)0);
    }
  }
  f32x4 accw[2];  // O @ Wo accumulator (persists across heads)
  accw[0] = (f32x4){0.f, 0.f, 0.f, 0.f};
  accw[1] = (f32x4){0.f, 0.f, 0.f, 0.f};

  for (int h = 0; h < H; ++h) {
    const unsigned short* fq = FQKV + (size_t)(h * 6) * 512;
    // ---- QKV projection ----
    f32x4 dq[2], dk[2], dv[2];
#pragma unroll
    for (int nt = 0; nt < 2; ++nt) {
      short8 bq = *reinterpret_cast<const short8*>(fq + (0 + nt) * 512 + lane * 8);
      dq[nt] = __builtin_amdgcn_mfma_f32_16x16x32_bf16(ax, bq, (f32x4){0.f, 0.f, 0.f, 0.f}, 0, 0, 0);
      short8 bk = *reinterpret_cast<const short8*>(fq + (2 + nt) * 512 + lane * 8);
      dk[nt] = __builtin_amdgcn_mfma_f32_16x16x32_bf16(ax, bk, (f32x4){0.f, 0.f, 0.f, 0.f}, 0, 0, 0);
      short8 bv = *reinterpret_cast<const short8*>(fq + (4 + nt) * 512 + lane * 8);
      dv[nt] = __builtin_amdgcn_mfma_f32_16x16x32_bf16(ax, bv, (f32x4){0.f, 0.f, 0.f, 0.f}, 0, 0, 0);
    }
    // write Qb/Kb ([pos][d]) and Vt ([d][pos])
#pragma unroll
    for (int nt = 0; nt < 2; ++nt) {
#pragma unroll
      for (int r = 0; r < 4; ++r) {
        const int pos = w * 16 + lg * 4 + r;
        const int d = nt * 16 + lr;
        Qb[pos * 40 + d] = f2bf(dq[nt][r]);
        Kb[pos * 40 + d] = f2bf(dk[nt][r]);
        Vt[d * 72 + pos] = f2bf(dv[nt][r]);
      }
    }
    __syncthreads();  // bar1: Qb/Kb/Vt complete

    // ---- S^T = K @ Q^T for query tile w: lane holds col i = w*16+lr, rows j ----
    short8 bqf = *reinterpret_cast<const short8*>(&Qb[(w * 16 + lr) * 40 + lg * 8]);
    f32x4 st[4];
#pragma unroll
    for (int mt = 0; mt < 4; ++mt) {
      short8 akf = *reinterpret_cast<const short8*>(&Kb[(mt * 16 + lr) * 40 + lg * 8]);
      st[mt] = __builtin_amdgcn_mfma_f32_16x16x32_bf16(akf, bqf, (f32x4){0.f, 0.f, 0.f, 0.f}, 0, 0, 0);
    }
    // ---- softmax over j (16 local + xor-reduce over lane-groups) ----
    float mx = -1e30f;
#pragma unroll
    for (int mt = 0; mt < 4; ++mt)
#pragma unroll
      for (int r = 0; r < 4; ++r) {
        const int j = mt * 16 + lg * 4 + r;
        float sv = (j < S) ? st[mt][r] : -1e30f;
        st[mt][r] = sv;
        mx = fmaxf(mx, sv);
      }
    mx = fmaxf(mx, __shfl_xor(mx, 16));
    mx = fmaxf(mx, __shfl_xor(mx, 32));
    float sum = 0.f;
#pragma unroll
    for (int mt = 0; mt < 4; ++mt)
#pragma unroll
      for (int r = 0; r < 4; ++r) {
        float e = __expf(st[mt][r] - mx);  // masked rows underflow to 0
        st[mt][r] = e;
        sum += e;
      }
    sum += __shfl_xor(sum, 16);
    sum += __shfl_xor(sum, 32);
    // write P^T rows i = w*16+lr (wave-private)
#pragma unroll
    for (int mt = 0; mt < 4; ++mt) {
#pragma unroll
      for (int s2 = 0; s2 < 2; ++s2) {
        unsigned pk = (unsigned)f2bf(st[mt][2 * s2]) | ((unsigned)f2bf(st[mt][2 * s2 + 1]) << 16);
        *reinterpret_cast<unsigned*>(&Pt[(w * 16 + lr) * 72 + mt * 16 + lg * 4 + 2 * s2]) = pk;
      }
    }
    // ---- PV: O^T = V^T @ P (N-tile w; reads own Pt rows, all Vt) ----
    short8 bp0 = *reinterpret_cast<const short8*>(&Pt[(w * 16 + lr) * 72 + lg * 8]);
    short8 bp1 = *reinterpret_cast<const short8*>(&Pt[(w * 16 + lr) * 72 + 32 + lg * 8]);
    f32x4 ot[2];
    ot[0] = (f32x4){0.f, 0.f, 0.f, 0.f};
    ot[1] = (f32x4){0.f, 0.f, 0.f, 0.f};
#pragma unroll
    for (int mt = 0; mt < 2; ++mt) {
      short8 av0 = *reinterpret_cast<const short8*>(&Vt[(mt * 16 + lr) * 72 + lg * 8]);
      ot[mt] = __builtin_amdgcn_mfma_f32_16x16x32_bf16(av0, bp0, ot[mt], 0, 0, 0);
      short8 av1 = *reinterpret_cast<const short8*>(&Vt[(mt * 16 + lr) * 72 + 32 + lg * 8]);
      ot[mt] = __builtin_amdgcn_mfma_f32_16x16x32_bf16(av1, bp1, ot[mt], 0, 0, 0);
    }
    // normalize (sum is in-lane: col i = lr preserved) and write Oh[i][d]
    const float inv = __builtin_amdgcn_rcpf(sum);
#pragma unroll
    for (int mt = 0; mt < 2; ++mt) {
#pragma unroll
      for (int s2 = 0; s2 < 2; ++s2) {
        unsigned pk = (unsigned)f2bf(ot[mt][2 * s2] * inv) |
                      ((unsigned)f2bf(ot[mt][2 * s2 + 1] * inv) << 16);
        *reinterpret_cast<unsigned*>(&Oh[(w * 16 + lr) * 40 + mt * 16 + lg * 4 + 2 * s2]) = pk;
      }
    }
    // ---- Wo accumulate: K-dim = d (pad 32, one step) ----
    short8 ao = *reinterpret_cast<const short8*>(&Oh[(w * 16 + lr) * 40 + lg * 8]);
#pragma unroll
    for (int nt = 0; nt < 2; ++nt) {
      short8 bw = *reinterpret_cast<const short8*>(FWo + (size_t)(h * 2 + nt) * 512 + lane * 8);
      accw[nt] = __builtin_amdgcn_mfma_f32_16x16x32_bf16(ao, bw, accw[nt], 0, 0, 0);
    }
    __syncthreads();  // bar2: Qb/Kb/Vt reads done -> next head may overwrite
  }

  // ---- epilogue: residual + LayerNorm; lane holds cols v={lr, 16+lr}, rows pos ----
#pragma unroll
  for (int r = 0; r < 4; ++r) {
    const int pos = w * 16 + lg * 4 + r;
    const bool v1ok = (lr < 5);
    const float x0 = (pos < S) ? X1f[pos * 21 + lr] : 0.f;
    const float x1 = (v1ok && pos < S) ? X1f[pos * 21 + 16 + lr] : 0.f;
    float z0 = accw[0][r] + x0;
    float z1 = v1ok ? (accw[1][r] + x1) : 0.f;
    float s = z0 + z1;
    s += __shfl_xor(s, 1); s += __shfl_xor(s, 2);
    s += __shfl_xor(s, 4); s += __shfl_xor(s, 8);
    const float mn = s * (1.f / V);
    const float d0 = z0 - mn;
    const float d1 = v1ok ? (z1 - mn) : 0.f;
    float vq = d0 * d0 + d1 * d1;
    vq += __shfl_xor(vq, 1); vq += __shfl_xor(vq, 2);
    vq += __shfl_xor(vq, 4); vq += __shfl_xor(vq, 8);
    const float inv = rsqrtf(vq * (1.f / V) + EPSF);
    if (pos < S) {
      X2[(size_t)b * SV + pos * 21 + lr] = d0 * inv * lng[lr] + lnb[lr];
      if (v1ok)
        X2[(size_t)b * SV + pos * 21 + 16 + lr] = d1 * inv * lng[16 + lr] + lnb[16 + lr];
    }
  }
}

// ---------------- K5: head GEMM [B,1239]@[1239,800] + bias + silu + BN -> Hb ----------------
constexpr int BT = 8;
constexpr int NT = 200;
__global__ __launch_bounds__(256) void k_f1(
    const float* __restrict__ X2, const float* __restrict__ Wf1, const float* __restrict__ bf1,
    const float* __restrict__ g2, const float* __restrict__ bb2, const float* __restrict__ m2,
    const float* __restrict__ v2, float* __restrict__ Hb) {
  __shared__ __align__(16) float Xs[BT * 1240];
  const int t = threadIdx.x;
  const int bbase = blockIdx.x * BT;
  const int nbase = blockIdx.y * NT;
  for (int i = t; i < BT * SV; i += 256) {
    int r = i / SV, f = i - r * SV;
    Xs[r * 1240 + f] = X2[(size_t)(bbase + r) * SV + f];
  }
  __syncthreads();
  if (t < NT) {
    const int n = nbase + t;
    float acc[BT];
#pragma unroll
    for (int r = 0; r < BT; ++r) acc[r] = 0.f;
    int f = 0;
    for (; f + 3 < SV; f += 4) {
      const float w0 = Wf1[(size_t)f * NH + n];
      const float w1 = Wf1[(size_t)(f + 1) * NH + n];
      const float w2 = Wf1[(size_t)(f + 2) * NH + n];
      const float w3 = Wf1[(size_t)(f + 3) * NH + n];
#pragma unroll
      for (int r = 0; r < BT; ++r) {
        const float4 x = *reinterpret_cast<const float4*>(&Xs[r * 1240 + f]);
        acc[r] = fmaf(x.x, w0, acc[r]);
        acc[r] = fmaf(x.y, w1, acc[r]);
        acc[r] = fmaf(x.z, w2, acc[r]);
        acc[r] = fmaf(x.w, w3, acc[r]);
      }
    }
    for (; f < SV; ++f) {
      const float w0 = Wf1[(size_t)f * NH + n];
#pragma unroll
      for (int r = 0; r < BT; ++r) acc[r] = fmaf(Xs[r * 1240 + f], w0, acc[r]);
    }
    const float sc = g2[n] * rsqrtf(v2[n] + EPSF);
    const float sh = bb2[n] - m2[n] * sc;
    const float bias = bf1[n];
#pragma unroll
    for (int r = 0; r < BT; ++r) {
      float hh = acc[r] + bias;
      hh = hh * sigm(hh);
      hh = fmaf(hh, sc, sh);
      Hb[(size_t)(bbase + r) * NH + n] = hh;
    }
  }
}

// ---------------- K6: relu(Hb@Wf2+bf2) @ Wf3 + bf3 -> out [B,2] ----------------
__global__ __launch_bounds__(64) void k_f23(
    const float* __restrict__ Hb, const float* __restrict__ Wf2, const float* __restrict__ bf2,
    const float* __restrict__ Wf3, const float* __restrict__ bf3, float* __restrict__ out) {
  __shared__ __align__(16) float hs[NH];
  const int t = threadIdx.x;
  const int b = blockIdx.x;
  for (int i = t; i < NH; i += 64) hs[i] = Hb[(size_t)b * NH + i];
  __syncthreads();
  float acc = bf2[t];
  for (int n = 0; n < NH; n += 4) {
    const float4 hv = *reinterpret_cast<const float4*>(&hs[n]);
    acc = fmaf(hv.x, Wf2[n * 64 + t], acc);
    acc = fmaf(hv.y, Wf2[(n + 1) * 64 + t], acc);
    acc = fmaf(hv.z, Wf2[(n + 2) * 64 + t], acc);
    acc = fmaf(hv.w, Wf2[(n + 3) * 64 + t], acc);
  }
  const float mid = fmaxf(acc, 0.f);
  float p0 = mid * Wf3[t * 2 + 0];
  float p1 = mid * Wf3[t * 2 + 1];
#pragma unroll
  for (int off = 32; off > 0; off >>= 1) {
    p0 += __shfl_down(p0, off);
    p1 += __shfl_down(p1, off);
  }
  if (t == 0) {
    out[b * 2 + 0] = p0 + bf3[0];
    out[b * 2 + 1] = p1 + bf3[1];
  }
}

}  // namespace

extern "C" void kernel_launch(void* const* d_in, const int* in_sizes, int n_in,
                              void* d_out, int out_size, void* d_ws, size_t ws_size,
                              hipStream_t stream) {
  const float* pep   = (const float*)d_in[0];
  const float* mhc   = (const float*)d_in[1];
  const float* W1    = (const float*)d_in[2];
  const float* b1    = (const float*)d_in[3];
  const float* Wd    = (const float*)d_in[4];
  const float* bd    = (const float*)d_in[5];
  const float* bn1_g = (const float*)d_in[6];
  const float* bn1_b = (const float*)d_in[7];
  const float* bn1_m = (const float*)d_in[8];
  const float* bn1_v = (const float*)d_in[9];
  const float* W2    = (const float*)d_in[10];
  const float* b2    = (const float*)d_in[11];
  const float* ln_g  = (const float*)d_in[12];
  const float* ln_b  = (const float*)d_in[13];
  const float* Wq    = (const float*)d_in[14];
  const float* Wk    = (const float*)d_in[15];
  const float* Wv    = (const float*)d_in[16];
  const float* Wo    = (const float*)d_in[17];
  const float* Wf1   = (const float*)d_in[18];
  const float* bf1   = (const float*)d_in[19];
  const float* bn2_g = (const float*)d_in[20];
  const float* bn2_b = (const float*)d_in[21];
  const float* bn2_m = (const float*)d_in[22];
  const float* bn2_v = (const float*)d_in[23];
  const float* Wf2   = (const float*)d_in[24];
  const float* bf2   = (const float*)d_in[25];
  const float* Wf3   = (const float*)d_in[26];
  const float* bf3   = (const float*)d_in[27];
  float* out = (float*)d_out;

  float* ws = (float*)d_ws;
  float* X1 = ws;                               // [B,59,21]
  float* X2 = X1 + (size_t)B * SV;              // [B,59,21]
  float* Hb = X2 + (size_t)B * SV;              // [B,800]
  float* TAP = Hb + (size_t)B * NH;             // [C,12]
  unsigned short* FB1  = (unsigned short*)(TAP + (size_t)C * 12);
  unsigned short* FB2  = FB1 + (size_t)400 * 512;
  unsigned short* FQKV = FB2 + (size_t)200 * 512;
  unsigned short* FWo  = FQKV + (size_t)54 * 512;

  k_packW<<<181, 256, 0, stream>>>(W1, Wd, bd, bn1_g, bn1_b, bn1_m, bn1_v, W2,
                                   Wq, Wk, Wv, Wo, FB1, FB2, FQKV, FWo, TAP);
  k_conv<<<B, 256, 0, stream>>>(pep, mhc, FB1, FB2, TAP, b1, b2, ln_g, ln_b, X1);
  k_attn<<<B, 256, 0, stream>>>(X1, FQKV, FWo, ln_g, ln_b, X2);
  dim3 g5(B / BT, NH / NT);
  k_f1<<<g5, 256, 0, stream>>>(X2, Wf1, bf1, bn2_g, bn2_b, bn2_m, bn2_v, Hb);
  k_f23<<<B, 64, 0, stream>>>(Hb, Wf2, bf2, Wf3, bf3, out);
}

// Round 10
// 367.568 us; speedup vs baseline: 2.8632x; 1.0260x over previous
//
#include <hip/hip_runtime.h>
#include <hip/hip_bf16.h>

namespace {

constexpr int B   = 1024;
constexpr int PEP = 15;
constexpr int MHCN = 44;
constexpr int S   = 59;    // sequence
constexpr int V   = 21;    // vocab / model dim
constexpr int C   = 3200;  // conv channels
constexpr int KW  = 9;     // depthwise kernel
constexpr int H   = 9;     // heads
constexpr int NH  = 800;
constexpr int SV  = S * V;   // 1239
constexpr int HD  = H * V;   // 189
constexpr float EPSF = 1e-5f;

typedef __attribute__((ext_vector_type(8))) short short8;   // 8 bf16 (4 VGPRs)
typedef __attribute__((ext_vector_type(4))) float f32x4;    // MFMA C/D frag

__device__ __forceinline__ float sigm(float x) {
  return __builtin_amdgcn_rcpf(1.f + __expf(-x));
}
__device__ __forceinline__ unsigned short f2bf(float f) {
  union { float f; unsigned u; } v; v.f = f;
  unsigned r = v.u + 0x7FFF + ((v.u >> 16) & 1);  // RNE
  return (unsigned short)(r >> 16);
}
__device__ __forceinline__ unsigned pkbf(float a, float b) {
  __hip_bfloat162 h = __float22bfloat162_rn(float2{a, b});
  return *reinterpret_cast<unsigned*>(&h);  // a in low 16, b in high 16
}

// ---------------- K0: pack all weights into MFMA B-fragment order (bf16) ----------------
// Frag convention (R8-verified): mfma(Afrag,Bfrag)=A@B^T with A[m=lr][k=lg*8+j],
// B[n=lr][k=lg*8+j], D[row=lg*4+reg][col=lr].
// FB1 k=21 slot carries b1 (bias folded via A col21=1.0).
__global__ void k_packW(const float* __restrict__ W1, const float* __restrict__ b1,
                        const float* __restrict__ Wd,
                        const float* __restrict__ bd, const float* __restrict__ g,
                        const float* __restrict__ bb, const float* __restrict__ m,
                        const float* __restrict__ vv, const float* __restrict__ W2,
                        const float* __restrict__ Wq, const float* __restrict__ Wk,
                        const float* __restrict__ Wv, const float* __restrict__ Wo,
                        unsigned short* __restrict__ FB1, unsigned short* __restrict__ FB2,
                        unsigned short* __restrict__ FQKV, unsigned short* __restrict__ FWo,
                        float* __restrict__ TAP) {
  int id = blockIdx.x * 256 + threadIdx.x;
  if (id < 400 * 64) {                       // FB1 (+bias at k==V)
    int tau = id >> 6, l = id & 63;
    int ci = tau >> 3, tt = tau & 7;
    int lr = l & 15, lg = l >> 4;
    int row = (tt < 4) ? (ci * 64 + tt * 16 + lr) : (C + ci * 64 + (tt - 4) * 16 + lr);
    for (int j = 0; j < 8; ++j) {
      int k = lg * 8 + j;
      float val = (k < V) ? W1[row * V + k] : (k == V ? b1[row] : 0.f);
      FB1[(size_t)tau * 512 + l * 8 + j] = f2bf(val);
    }
  } else if (id < 38400) {                   // FB2
    int id2 = id - 25600;
    int sg = id2 >> 6, l = id2 & 63;
    int ci = sg >> 2, rem = sg & 3, kt = rem >> 1, nt = rem & 1;
    int lr = l & 15, lg = l >> 4;
    int vc = nt * 16 + lr;
    for (int j = 0; j < 8; ++j) {
      int ch = ci * 64 + kt * 32 + lg * 8 + j;
      float val = (vc < V) ? W2[(size_t)vc * C + ch] : 0.f;
      FB2[(size_t)sg * 512 + l * 8 + j] = f2bf(val);
    }
  } else if (id < 41856) {                   // FQKV: 9h x 3mat x 2nt tiles
    int id2 = id - 38400;
    int tile = id2 >> 6, l = id2 & 63;
    int h = tile / 6, rem = tile - h * 6;
    int mat = rem >> 1, nt = rem & 1;
    int lr = l & 15, kg = l >> 4;
    int dcol = nt * 16 + lr;
    const float* W = (mat == 0) ? Wq : (mat == 1) ? Wk : Wv;
    const float scale = (mat == 0) ? 0.21821789023599236f : 1.f;  // 1/sqrt(21) into Q
    for (int j = 0; j < 8; ++j) {
      int u = kg * 8 + j;
      float val = (u < V && dcol < V) ? W[u * HD + h * V + dcol] * scale : 0.f;
      FQKV[(size_t)tile * 512 + l * 8 + j] = f2bf(val);
    }
  } else if (id < 43008) {                   // FWo: 9h x 2nt tiles, k = head-dim d
    int id2 = id - 41856;
    int tile = id2 >> 6, l = id2 & 63;
    int h = tile >> 1, nt = tile & 1;
    int lr = l & 15, kg = l >> 4;
    int vcol = nt * 16 + lr;
    for (int j = 0; j < 8; ++j) {
      int d = kg * 8 + j;
      float val = (d < V && vcol < V) ? Wo[(h * V + d) * V + vcol] : 0.f;
      FWo[(size_t)tile * 512 + l * 8 + j] = f2bf(val);
    }
  } else {                                   // TAP
    int c = id - 43008;
    if (c < C) {
      float sc = g[c] * rsqrtf(vv[c] + EPSF);
      for (int k = 0; k < KW; ++k) TAP[c * 12 + k] = Wd[c * KW + k] * sc;
      TAP[c * 12 + 9]  = (bd[c] - m[c]) * sc + bb[c];
      TAP[c * 12 + 10] = 0.f;
      TAP[c * 12 + 11] = 0.f;
    }
  }
}

// ---------------- K2: MFMA conv module + residual + LN -> X1 ----------------
// R10: lean codegen — loop-invariant LDS/global pointers, biases folded into
// MFMA (A col21 = 1.0), minimal per-chunk address math.
__global__ __launch_bounds__(256) void k_conv(
    const float* __restrict__ pep, const float* __restrict__ mhc,
    const unsigned short* __restrict__ FB1, const unsigned short* __restrict__ FB2,
    const float* __restrict__ TAP,
    const float* __restrict__ b2, const float* __restrict__ lng,
    const float* __restrict__ lnb, float* __restrict__ X1) {
  __shared__ __align__(16) unsigned short Xbf[64 * 40];
  __shared__ float glbuf[64 * 73];
  __shared__ __align__(16) unsigned short Sbuf[4][16 * 72];
  __shared__ float yfull[SV];
  const int t = threadIdx.x;
  const int b = blockIdx.x;
  const int lane = t & 63;
  const int w = t >> 6;
  const int lr = lane & 15;
  const int lg = lane >> 4;

  for (int i = t; i < 64 * 4; i += 256) glbuf[(i >> 2) * 73 + (i & 3)] = 0.f;
  {
    const int row = t >> 2, q = t & 3;
    const float* xr = (row < PEP) ? pep + ((size_t)b * PEP + row) * V
                    : (row < S)   ? mhc + ((size_t)b * MHCN + (row - PEP)) * V
                                  : nullptr;
#pragma unroll
    for (int i2 = 0; i2 < 5; ++i2) {
      int c0 = q * 10 + 2 * i2;
      float f0 = (xr && c0 < V) ? xr[c0] : 0.f;
      float f1 = (xr && c0 + 1 < V) ? xr[c0 + 1] : ((xr && c0 + 1 == V) ? 1.f : 0.f);
      *reinterpret_cast<unsigned*>(&Xbf[row * 40 + c0]) = pkbf(f0, f1);
    }
  }
  __syncthreads();

  short8 ax = *reinterpret_cast<const short8*>(&Xbf[(w * 16 + lr) * 40 + lg * 8]);
  f32x4 acc2[2];
  acc2[0] = (f32x4){0.f, 0.f, 0.f, 0.f};
  acc2[1] = (f32x4){0.f, 0.f, 0.f, 0.f};
  const int mypos = w * 16 + lg * 4;

  // loop-invariant addresses
  float* glw0 = &glbuf[lr * 73 + 4 + mypos];               // + tt*16*73, + r
  const float* glr = &glbuf[lane * 73 + w * 16];           // + i2
  unsigned short* sbw = &Sbuf[w][lane];                    // + i2*72
  const unsigned short* sbr = &Sbuf[w][lr * 72 + lg * 8];  // + kt*32
  const unsigned short* fb1p = FB1 + lane * 8;             // + tt*512; += 4096/chunk
  const unsigned short* fb2p = FB2 + lane * 8;             // + sg*512; += 2048/chunk
  const float* tapp = TAP + lane * 12;                     // += 768/chunk

  for (int ci = 0; ci < C / 64; ++ci) {
    f32x4 ga[4], gg[4];
#pragma unroll
    for (int tt = 0; tt < 4; ++tt) {
      short8 bf = *reinterpret_cast<const short8*>(fb1p + tt * 512);
      ga[tt] = __builtin_amdgcn_mfma_f32_16x16x32_bf16(ax, bf, (f32x4){0.f, 0.f, 0.f, 0.f}, 0, 0, 0);
    }
#pragma unroll
    for (int tt = 0; tt < 4; ++tt) {
      short8 bf = *reinterpret_cast<const short8*>(fb1p + (4 + tt) * 512);
      gg[tt] = __builtin_amdgcn_mfma_f32_16x16x32_bf16(ax, bf, (f32x4){0.f, 0.f, 0.f, 0.f}, 0, 0, 0);
    }
    // ---- GLU epilogue (bias already in D): gl = a * sigm(g) ----
#pragma unroll
    for (int tt = 0; tt < 4; ++tt) {
      float* gw = glw0 + tt * (16 * 73);
#pragma unroll
      for (int r = 0; r < 4; ++r) {
        float gl = ga[tt][r] * sigm(gg[tt][r]);
        gw[r] = (mypos + r < S) ? gl : 0.f;
      }
    }
    __syncthreads();  // bar1: glbuf complete
    // ---- depthwise conv + shift + SiLU -> Sbuf bf16 (wave-private) ----
    {
      const float4 t0 = *reinterpret_cast<const float4*>(tapp);
      const float4 t1 = *reinterpret_cast<const float4*>(tapp + 4);
      const float4 t2 = *reinterpret_cast<const float4*>(tapp + 8);
      const float tap[9] = {t0.x, t0.y, t0.z, t0.w, t1.x, t1.y, t1.z, t1.w, t2.x};
      const float sh = t2.y;
      float gv[24];
#pragma unroll
      for (int i2 = 0; i2 < 24; ++i2) gv[i2] = glr[i2];
#pragma unroll
      for (int i2 = 0; i2 < 16; ++i2) {
        float a = sh;
#pragma unroll
        for (int k = 0; k < KW; ++k) a = fmaf(gv[i2 + k], tap[k], a);
        const float sb = a * sigm(a);
        sbw[i2 * 72] = (w * 16 + i2 < S) ? f2bf(sb) : (unsigned short)0;
      }
    }
    // ---- down-proj MFMAs (wave-synchronous Sbuf read) ----
#pragma unroll
    for (int kt = 0; kt < 2; ++kt) {
      short8 a2f = *reinterpret_cast<const short8*>(sbr + kt * 32);
#pragma unroll
      for (int nt = 0; nt < 2; ++nt) {
        short8 b2f = *reinterpret_cast<const short8*>(fb2p + (kt * 2 + nt) * 512);
        acc2[nt] = __builtin_amdgcn_mfma_f32_16x16x32_bf16(a2f, b2f, acc2[nt], 0, 0, 0);
      }
    }
    __syncthreads();  // bar2: glbuf reads done -> next chunk may overwrite
    fb1p += 8 * 512;
    fb2p += 4 * 512;
    tapp += 64 * 12;
  }

#pragma unroll
  for (int nt = 0; nt < 2; ++nt) {
#pragma unroll
    for (int r = 0; r < 4; ++r) {
      const int pos = mypos + r, vc = nt * 16 + lr;
      if (pos < S && vc < V) yfull[pos * V + vc] = acc2[nt][r];
    }
  }
  __syncthreads();

  if (t < S) {
    const float* xr = (t < PEP) ? pep + ((size_t)b * PEP + t) * V
                                : mhc + ((size_t)b * MHCN + (t - PEP)) * V;
    float z[V];
    float mn = 0.f;
#pragma unroll
    for (int v = 0; v < V; ++v) {
      z[v] = xr[v] + yfull[t * V + v] + b2[v];
      mn += z[v];
    }
    mn *= (1.f / V);
    float var = 0.f;
#pragma unroll
    for (int v = 0; v < V; ++v) {
      float d = z[v] - mn;
      var = fmaf(d, d, var);
    }
    const float inv = rsqrtf(var * (1.f / V) + EPSF);
#pragma unroll
    for (int v = 0; v < V; ++v)
      X1[(size_t)b * SV + t * V + v] = (z[v] - mn) * inv * lng[v] + lnb[v];
  }
}

// ---------------- K3: fused MFMA attention + Wo + residual + LN -> X2 ----------------
__global__ __launch_bounds__(256) void k_attn(
    const float* __restrict__ X1, const unsigned short* __restrict__ FQKV,
    const unsigned short* __restrict__ FWo, const float* __restrict__ lng,
    const float* __restrict__ lnb, float* __restrict__ X2) {
  __shared__ float X1f[64 * 21];
  __shared__ __align__(16) unsigned short Qb[64 * 40];
  __shared__ __align__(16) unsigned short Kb[64 * 40];
  __shared__ __align__(16) unsigned short Vt[32 * 72];
  __shared__ __align__(16) unsigned short Pt[64 * 72];
  __shared__ __align__(16) unsigned short Oh[64 * 40];
  const int t = threadIdx.x;
  const int b = blockIdx.x;
  const int lane = t & 63;
  const int w = t >> 6;
  const int lr = lane & 15;
  const int lg = lane >> 4;

  for (int i = t; i < 64 * 21; i += 256)
    X1f[i] = (i < SV) ? X1[(size_t)b * SV + i] : 0.f;
  __syncthreads();

  short8 ax;
  {
    const int rowi = w * 16 + lr;
#pragma unroll
    for (int j = 0; j < 8; ++j) {
      int col = lg * 8 + j;
      ax[j] = (short)((col < V) ? f2bf(X1f[rowi * 21 + col]) : (unsigned short)0);
    }
  }
  f32x4 accw[2];
  accw[0] = (f32x4){0.f, 0.f, 0.f, 0.f};
  accw[1] = (f32x4){0.f, 0.f, 0.f, 0.f};

  for (int h = 0; h < H; ++h) {
    const unsigned short* fq = FQKV + (size_t)(h * 6) * 512;
    f32x4 dq[2], dk[2], dv[2];
#pragma unroll
    for (int nt = 0; nt < 2; ++nt) {
      short8 bq = *reinterpret_cast<const short8*>(fq + (0 + nt) * 512 + lane * 8);
      dq[nt] = __builtin_amdgcn_mfma_f32_16x16x32_bf16(ax, bq, (f32x4){0.f, 0.f, 0.f, 0.f}, 0, 0, 0);
      short8 bk = *reinterpret_cast<const short8*>(fq + (2 + nt) * 512 + lane * 8);
      dk[nt] = __builtin_amdgcn_mfma_f32_16x16x32_bf16(ax, bk, (f32x4){0.f, 0.f, 0.f, 0.f}, 0, 0, 0);
      short8 bv = *reinterpret_cast<const short8*>(fq + (4 + nt) * 512 + lane * 8);
      dv[nt] = __builtin_amdgcn_mfma_f32_16x16x32_bf16(ax, bv, (f32x4){0.f, 0.f, 0.f, 0.f}, 0, 0, 0);
    }
#pragma unroll
    for (int nt = 0; nt < 2; ++nt) {
#pragma unroll
      for (int r = 0; r < 4; ++r) {
        const int pos = w * 16 + lg * 4 + r;
        const int d = nt * 16 + lr;
        Qb[pos * 40 + d] = f2bf(dq[nt][r]);
        Kb[pos * 40 + d] = f2bf(dk[nt][r]);
        Vt[d * 72 + pos] = f2bf(dv[nt][r]);
      }
    }
    __syncthreads();  // bar1: Qb/Kb/Vt complete

    short8 bqf = *reinterpret_cast<const short8*>(&Qb[(w * 16 + lr) * 40 + lg * 8]);
    f32x4 st[4];
#pragma unroll
    for (int mt = 0; mt < 4; ++mt) {
      short8 akf = *reinterpret_cast<const short8*>(&Kb[(mt * 16 + lr) * 40 + lg * 8]);
      st[mt] = __builtin_amdgcn_mfma_f32_16x16x32_bf16(akf, bqf, (f32x4){0.f, 0.f, 0.f, 0.f}, 0, 0, 0);
    }
    float mx = -1e30f;
#pragma unroll
    for (int mt = 0; mt < 4; ++mt)
#pragma unroll
      for (int r = 0; r < 4; ++r) {
        const int j = mt * 16 + lg * 4 + r;
        float sv = (j < S) ? st[mt][r] : -1e30f;
        st[mt][r] = sv;
        mx = fmaxf(mx, sv);
      }
    mx = fmaxf(mx, __shfl_xor(mx, 16));
    mx = fmaxf(mx, __shfl_xor(mx, 32));
    float sum = 0.f;
#pragma unroll
    for (int mt = 0; mt < 4; ++mt)
#pragma unroll
      for (int r = 0; r < 4; ++r) {
        float e = __expf(st[mt][r] - mx);
        st[mt][r] = e;
        sum += e;
      }
    sum += __shfl_xor(sum, 16);
    sum += __shfl_xor(sum, 32);
#pragma unroll
    for (int mt = 0; mt < 4; ++mt) {
#pragma unroll
      for (int s2 = 0; s2 < 2; ++s2) {
        *reinterpret_cast<unsigned*>(&Pt[(w * 16 + lr) * 72 + mt * 16 + lg * 4 + 2 * s2]) =
            pkbf(st[mt][2 * s2], st[mt][2 * s2 + 1]);
      }
    }
    short8 bp0 = *reinterpret_cast<const short8*>(&Pt[(w * 16 + lr) * 72 + lg * 8]);
    short8 bp1 = *reinterpret_cast<const short8*>(&Pt[(w * 16 + lr) * 72 + 32 + lg * 8]);
    f32x4 ot[2];
    ot[0] = (f32x4){0.f, 0.f, 0.f, 0.f};
    ot[1] = (f32x4){0.f, 0.f, 0.f, 0.f};
#pragma unroll
    for (int mt = 0; mt < 2; ++mt) {
      short8 av0 = *reinterpret_cast<const short8*>(&Vt[(mt * 16 + lr) * 72 + lg * 8]);
      ot[mt] = __builtin_amdgcn_mfma_f32_16x16x32_bf16(av0, bp0, ot[mt], 0, 0, 0);
      short8 av1 = *reinterpret_cast<const short8*>(&Vt[(mt * 16 + lr) * 72 + 32 + lg * 8]);
      ot[mt] = __builtin_amdgcn_mfma_f32_16x16x32_bf16(av1, bp1, ot[mt], 0, 0, 0);
    }
    const float inv = __builtin_amdgcn_rcpf(sum);
#pragma unroll
    for (int mt = 0; mt < 2; ++mt) {
#pragma unroll
      for (int s2 = 0; s2 < 2; ++s2) {
        *reinterpret_cast<unsigned*>(&Oh[(w * 16 + lr) * 40 + mt * 16 + lg * 4 + 2 * s2]) =
            pkbf(ot[mt][2 * s2] * inv, ot[mt][2 * s2 + 1] * inv);
      }
    }
    short8 ao = *reinterpret_cast<const short8*>(&Oh[(w * 16 + lr) * 40 + lg * 8]);
#pragma unroll
    for (int nt = 0; nt < 2; ++nt) {
      short8 bw = *reinterpret_cast<const short8*>(FWo + (size_t)(h * 2 + nt) * 512 + lane * 8);
      accw[nt] = __builtin_amdgcn_mfma_f32_16x16x32_bf16(ao, bw, accw[nt], 0, 0, 0);
    }
    __syncthreads();  // bar2
  }

#pragma unroll
  for (int r = 0; r < 4; ++r) {
    const int pos = w * 16 + lg * 4 + r;
    const bool v1ok = (lr < 5);
    const float x0 = (pos < S) ? X1f[pos * 21 + lr] : 0.f;
    const float x1 = (v1ok && pos < S) ? X1f[pos * 21 + 16 + lr] : 0.f;
    float z0 = accw[0][r] + x0;
    float z1 = v1ok ? (accw[1][r] + x1) : 0.f;
    float s = z0 + z1;
    s += __shfl_xor(s, 1); s += __shfl_xor(s, 2);
    s += __shfl_xor(s, 4); s += __shfl_xor(s, 8);
    const float mn = s * (1.f / V);
    const float d0 = z0 - mn;
    const float d1 = v1ok ? (z1 - mn) : 0.f;
    float vq = d0 * d0 + d1 * d1;
    vq += __shfl_xor(vq, 1); vq += __shfl_xor(vq, 2);
    vq += __shfl_xor(vq, 4); vq += __shfl_xor(vq, 8);
    const float inv = rsqrtf(vq * (1.f / V) + EPSF);
    if (pos < S) {
      X2[(size_t)b * SV + pos * 21 + lr] = d0 * inv * lng[lr] + lnb[lr];
      if (v1ok)
        X2[(size_t)b * SV + pos * 21 + 16 + lr] = d1 * inv * lng[16 + lr] + lnb[16 + lr];
    }
  }
}

// ---------------- K5: head GEMM [B,1239]@[1239,800] + bias + silu + BN -> Hb ----------------
constexpr int BT = 8;
constexpr int NT = 200;
__global__ __launch_bounds__(256) void k_f1(
    const float* __restrict__ X2, const float* __restrict__ Wf1, const float* __restrict__ bf1,
    const float* __restrict__ g2, const float* __restrict__ bb2, const float* __restrict__ m2,
    const float* __restrict__ v2, float* __restrict__ Hb) {
  __shared__ __align__(16) float Xs[BT * 1240];
  const int t = threadIdx.x;
  const int bbase = blockIdx.x * BT;
  const int nbase = blockIdx.y * NT;
  for (int i = t; i < BT * SV; i += 256) {
    int r = i / SV, f = i - r * SV;
    Xs[r * 1240 + f] = X2[(size_t)(bbase + r) * SV + f];
  }
  __syncthreads();
  if (t < NT) {
    const int n = nbase + t;
    float acc[BT];
#pragma unroll
    for (int r = 0; r < BT; ++r) acc[r] = 0.f;
    int f = 0;
    for (; f + 3 < SV; f += 4) {
      const float w0 = Wf1[(size_t)f * NH + n];
      const float w1 = Wf1[(size_t)(f + 1) * NH + n];
      const float w2 = Wf1[(size_t)(f + 2) * NH + n];
      const float w3 = Wf1[(size_t)(f + 3) * NH + n];
#pragma unroll
      for (int r = 0; r < BT; ++r) {
        const float4 x = *reinterpret_cast<const float4*>(&Xs[r * 1240 + f]);
        acc[r] = fmaf(x.x, w0, acc[r]);
        acc[r] = fmaf(x.y, w1, acc[r]);
        acc[r] = fmaf(x.z, w2, acc[r]);
        acc[r] = fmaf(x.w, w3, acc[r]);
      }
    }
    for (; f < SV; ++f) {
      const float w0 = Wf1[(size_t)f * NH + n];
#pragma unroll
      for (int r = 0; r < BT; ++r) acc[r] = fmaf(Xs[r * 1240 + f], w0, acc[r]);
    }
    const float sc = g2[n] * rsqrtf(v2[n] + EPSF);
    const float sh = bb2[n] - m2[n] * sc;
    const float bias = bf1[n];
#pragma unroll
    for (int r = 0; r < BT; ++r) {
      float hh = acc[r] + bias;
      hh = hh * sigm(hh);
      hh = fmaf(hh, sc, sh);
      Hb[(size_t)(bbase + r) * NH + n] = hh;
    }
  }
}

// ---------------- K6: relu(Hb@Wf2+bf2) @ Wf3 + bf3 -> out [B,2] ----------------
__global__ __launch_bounds__(64) void k_f23(
    const float* __restrict__ Hb, const float* __restrict__ Wf2, const float* __restrict__ bf2,
    const float* __restrict__ Wf3, const float* __restrict__ bf3, float* __restrict__ out) {
  __shared__ __align__(16) float hs[NH];
  const int t = threadIdx.x;
  const int b = blockIdx.x;
  for (int i = t; i < NH; i += 64) hs[i] = Hb[(size_t)b * NH + i];
  __syncthreads();
  float acc = bf2[t];
  for (int n = 0; n < NH; n += 4) {
    const float4 hv = *reinterpret_cast<const float4*>(&hs[n]);
    acc = fmaf(hv.x, Wf2[n * 64 + t], acc);
    acc = fmaf(hv.y, Wf2[(n + 1) * 64 + t], acc);
    acc = fmaf(hv.z, Wf2[(n + 2) * 64 + t], acc);
    acc = fmaf(hv.w, Wf2[(n + 3) * 64 + t], acc);
  }
  const float mid = fmaxf(acc, 0.f);
  float p0 = mid * Wf3[t * 2 + 0];
  float p1 = mid * Wf3[t * 2 + 1];
#pragma unroll
  for (int off = 32; off > 0; off >>= 1) {
    p0 += __shfl_down(p0, off);
    p1 += __shfl_down(p1, off);
  }
  if (t == 0) {
    out[b * 2 + 0] = p0 + bf3[0];
    out[b * 2 + 1] = p1 + bf3[1];
  }
}

}  // namespace

extern "C" void kernel_launch(void* const* d_in, const int* in_sizes, int n_in,
                              void* d_out, int out_size, void* d_ws, size_t ws_size,
                              hipStream_t stream) {
  const float* pep   = (const float*)d_in[0];
  const float* mhc   = (const float*)d_in[1];
  const float* W1    = (const float*)d_in[2];
  const float* b1    = (const float*)d_in[3];
  const float* Wd    = (const float*)d_in[4];
  const float* bd    = (const float*)d_in[5];
  const float* bn1_g = (const float*)d_in[6];
  const float* bn1_b = (const float*)d_in[7];
  const float* bn1_m = (const float*)d_in[8];
  const float* bn1_v = (const float*)d_in[9];
  const float* W2    = (const float*)d_in[10];
  const float* b2    = (const float*)d_in[11];
  const float* ln_g  = (const float*)d_in[12];
  const float* ln_b  = (const float*)d_in[13];
  const float* Wq    = (const float*)d_in[14];
  const float* Wk    = (const float*)d_in[15];
  const float* Wv    = (const float*)d_in[16];
  const float* Wo    = (const float*)d_in[17];
  const float* Wf1   = (const float*)d_in[18];
  const float* bf1   = (const float*)d_in[19];
  const float* bn2_g = (const float*)d_in[20];
  const float* bn2_b = (const float*)d_in[21];
  const float* bn2_m = (const float*)d_in[22];
  const float* bn2_v = (const float*)d_in[23];
  const float* Wf2   = (const float*)d_in[24];
  const float* bf2   = (const float*)d_in[25];
  const float* Wf3   = (const float*)d_in[26];
  const float* bf3   = (const float*)d_in[27];
  float* out = (float*)d_out;

  float* ws = (float*)d_ws;
  float* X1 = ws;                               // [B,59,21]
  float* X2 = X1 + (size_t)B * SV;              // [B,59,21]
  float* Hb = X2 + (size_t)B * SV;              // [B,800]
  float* TAP = Hb + (size_t)B * NH;             // [C,12]
  unsigned short* FB1  = (unsigned short*)(TAP + (size_t)C * 12);
  unsigned short* FB2  = FB1 + (size_t)400 * 512;
  unsigned short* FQKV = FB2 + (size_t)200 * 512;
  unsigned short* FWo  = FQKV + (size_t)54 * 512;

  k_packW<<<181, 256, 0, stream>>>(W1, b1, Wd, bd, bn1_g, bn1_b, bn1_m, bn1_v, W2,
                                   Wq, Wk, Wv, Wo, FB1, FB2, FQKV, FWo, TAP);
  k_conv<<<B, 256, 0, stream>>>(pep, mhc, FB1, FB2, TAP, b2, ln_g, ln_b, X1);
  k_attn<<<B, 256, 0, stream>>>(X1, FQKV, FWo, ln_g, ln_b, X2);
  dim3 g5(B / BT, NH / NT);
  k_f1<<<g5, 256, 0, stream>>>(X2, Wf1, bf1, bn2_g, bn2_b, bn2_m, bn2_v, Hb);
  k_f23<<<B, 64, 0, stream>>>(Hb, Wf2, bf2, Wf3, bf3, out);
}